// Round 12
// baseline (538.601 us; speedup 1.0000x reference)
//
#include <hip/hip_runtime.h>
#include <cmath>

constexpr int Bq = 8, Lq = 32768, Dq = 64, Nq = 16, NLq = 4;
constexpr int CLq = 128, NCq = 256;           // NCq*CLq == Lq ; chunks per batch
constexpr int PT = Bq * Lq / 16;              // 16384 position-tiles of 16

typedef _Float16 f16;
typedef _Float16 half2t __attribute__((ext_vector_type(2)));
typedef _Float16 half4 __attribute__((ext_vector_type(4)));
typedef _Float16 half8 __attribute__((ext_vector_type(8)));
typedef float f32x4 __attribute__((ext_vector_type(4)));
typedef float f32x2 __attribute__((ext_vector_type(2)));

static __device__ __forceinline__ float sigm(float x) { return 1.0f / (1.0f + __expf(-x)); }
static __device__ __forceinline__ float gelu_t(float x) {
  return x * sigm(1.5957691216057308f * fmaf(0.044715f * x * x, x, x));
}

// -------- k_wtall: setup + all layers' frag-ordered f16 matrices TF/VF/WF; LCL, LC2K --------
__global__ __launch_bounds__(128) void k_wtall(
    const float* __restrict__ log_dt, const float* __restrict__ log_A_real,
    const float* __restrict__ A_imag, const float* __restrict__ C_re,
    const float* __restrict__ C_im, const float* __restrict__ dskip,
    f32x2* __restrict__ LCL, f32x2* __restrict__ LC2K, half8* __restrict__ TF,
    half8* __restrict__ VF, half8* __restrict__ WF) {
  __shared__ f32x2 pw[129][16];
  __shared__ f32x2 lamS[16], dcS[16];
  __shared__ float Ks[128];
  int d = blockIdx.x & 63, L = blockIdx.x >> 6;
  half8* TFl = TF + (size_t)L * 131072;
  half8* VFl = VF + (size_t)L * 32768;
  half8* WFl = WF + (size_t)L * 32768;
  int t = threadIdx.x;
  if (t < 16) {
    int di = L * 64 + d;
    int idx = di * 16 + t;
    float dt = expf(log_dt[di]);
    float Ar = -expf(log_A_real[idx]);
    float Ai = A_imag[idx];
    float dr = Ar * dt, dmi = Ai * dt;
    float er = expf(dr);
    float lr = er * cosf(dmi), li = er * sinf(dmi);
    float inv = 1.0f / (Ar * Ar + Ai * Ai);
    float e1r = lr - 1.0f, e1i = li;
    float qr = (e1r * Ar + e1i * Ai) * inv;
    float qi = (e1i * Ar - e1r * Ai) * inv;
    float cr = C_re[idx], ci = C_im[idx];
    lamS[t] = f32x2{lr, li};
    dcS[t] = f32x2{2.0f * (cr * qr - ci * qi), 2.0f * (cr * qi + ci * qr)};
    float erc = expf(dr * 128.0f);
    f32x2 l128 = f32x2{erc * cosf(dmi * 128.0f), erc * sinf(dmi * 128.0f)};
    pw[128][t] = l128;
    LCL[(size_t)L * 1024 + d * 16 + t] = l128;
    float br = l128.x, bi = l128.y;
#pragma unroll
    for (int q = 0; q < 4; q++) {
      float t2 = br * br - bi * bi;
      bi = 2.f * br * bi; br = t2;
    }
    LC2K[(size_t)L * 1024 + d * 16 + t] = f32x2{br, bi};
  }
  __syncthreads();
#pragma unroll
  for (int n = 0; n < 16; n++) {
    f32x2 lam = lamS[n];
    float pr = 1.f, pi = 0.f, br = lam.x, bi = lam.y;
    int e = t;
    while (e) {
      if (e & 1) { float tt = pr * br - pi * bi; pi = fmaf(pr, bi, pi * br); pr = tt; }
      float t2 = br * br - bi * bi; bi = 2.f * br * bi; br = t2; e >>= 1;
    }
    pw[t][n] = f32x2{pr, pi};
  }
  __syncthreads();
  {
    float k = 0.f;
#pragma unroll
    for (int n = 0; n < 16; n++) {
      f32x2 dc = dcS[n];
      f32x2 p = pw[t][n];
      k += dc.x * p.x - dc.y * p.y;
    }
    if (t == 0) k += dskip[L * 64 + d];
    Ks[t] = k;
  }
  __syncthreads();
  for (int s = t; s < 2048; s += 128) {
    int ln = s & 63, kt = (s >> 6) & 3, mt = s >> 8;
    int jo = mt * 16 + (ln & 15);
    int ji0 = kt * 32 + (ln >> 4) * 8;
    half8 v;
#pragma unroll
    for (int jj = 0; jj < 8; jj++) {
      int ji = ji0 + jj;
      v[jj] = (jo >= ji) ? (f16)Ks[jo - ji] : (f16)0.f;
    }
    TFl[(size_t)d * 2048 + s] = v;
  }
  for (int s = t; s < 512; s += 128) {
    int ln = s & 63, mt = s >> 6;
    int jo = mt * 16 + (ln & 15);
    int q0 = (ln >> 4) * 8;
    half8 v;
#pragma unroll
    for (int jj = 0; jj < 8; jj++) {
      int q = q0 + jj, n = q >> 1;
      f32x2 dc = dcS[n];
      f32x2 p = pw[jo + 1][n];
      float wr = dc.x * p.x - dc.y * p.y;
      float wi = dc.x * p.y + dc.y * p.x;
      v[jj] = (q & 1) ? (f16)(-wi) : (f16)wr;
    }
    VFl[(size_t)d * 512 + s] = v;
  }
  for (int s = t; s < 512; s += 128) {
    int ln = s & 63, kt = (s >> 6) & 3, nt = s >> 8;
    int p_ = nt * 16 + (ln & 15);
    int n = p_ >> 1;
    int j0 = kt * 32 + (ln >> 4) * 8;
    half8 v;
#pragma unroll
    for (int jj = 0; jj < 8; jj++) {
      f32x2 p = pw[127 - (j0 + jj)][n];
      v[jj] = (p_ & 1) ? (f16)p.y : (f16)p.x;
    }
    WFl[(size_t)d * 512 + s] = v;
  }
}

// -------- k_init3: x = relu(w_init*in + b_init) -> X f16; z = s4LN0(x) -> Z16 --------
__global__ __launch_bounds__(512) void k_init3(
    const float* __restrict__ inp, const float* __restrict__ w_init,
    const float* __restrict__ b_init, const float* __restrict__ lnw,
    const float* __restrict__ lnb, f16* __restrict__ X, f16* __restrict__ Z16) {
  __shared__ __align__(16) f16 ztile[64 * 132];
  int tid = threadIdx.x;
  int widx = tid >> 6, lane = tid & 63;
  int pl = lane & 15, qh = lane >> 4;
  for (int k = 0; k < 4; ++k) {
    int pt = blockIdx.x * 8 + widx + k * 4096;
    int pos = pt * 16 + pl;
    float v = inp[pos];
    float s = 0.f, s2 = 0.f;
    f32x4 o[4];
#pragma unroll
    for (int q = 0; q < 4; q++) {
      int d0 = q * 16 + qh * 4;
      f32x4 w4 = *(const f32x4*)(w_init + d0);
      f32x4 b4 = *(const f32x4*)(b_init + d0);
#pragma unroll
      for (int j = 0; j < 4; j++) {
        float t = fmaf(w4[j], v, b4[j]);
        t = t > 0.f ? t : 0.f;
        o[q][j] = t; s += t; s2 += t * t;
      }
      half4 xo = half4{(f16)o[q][0], (f16)o[q][1], (f16)o[q][2], (f16)o[q][3]};
      *(half4*)(X + (size_t)pos * 64 + d0) = xo;
    }
    s += __shfl_xor(s, 16); s += __shfl_xor(s, 32);
    s2 += __shfl_xor(s2, 16); s2 += __shfl_xor(s2, 32);
    float m = s * (1.0f / 64.0f);
    float rstd = rsqrtf(s2 * (1.0f / 64.0f) - m * m + 1e-5f);
    int prow = widx * 16 + pl;
#pragma unroll
    for (int q = 0; q < 4; q++) {
      int d0 = q * 16 + qh * 4;
      f32x4 lw = *(const f32x4*)(lnw + d0);
      f32x4 lb = *(const f32x4*)(lnb + d0);
#pragma unroll
      for (int r = 0; r < 4; r++)
        ztile[(d0 + r) * 132 + prow] = (f16)fmaf((o[q][r] - m) * rstd, lw[r], lb[r]);
    }
    __syncthreads();
    {
      int d = tid >> 3, c0 = (tid & 7) * 16;
      half8 z0 = *(const half8*)(ztile + d * 132 + c0);
      half8 z1 = *(const half8*)(ztile + d * 132 + c0 + 8);
      size_t zoff = (size_t)d * 262144 + (size_t)(blockIdx.x * 8 + k * 4096) * 16;
      *(half8*)(Z16 + zoff + c0) = z0;
      *(half8*)(Z16 + zoff + c0 + 8) = z1;
    }
    __syncthreads();
  }
}

// -------- k_p1g: chunk end-states S16[d][bc][p32] = Z(m=bc,k=j) @ Wend(k=j,n=p) --------
__global__ __launch_bounds__(256) void k_p1g(
    const f16* __restrict__ Z16, const half8* __restrict__ WF, f16* __restrict__ S16) {
  int tid = threadIdx.x;
  int lane = tid & 63;
  int task = blockIdx.x * 4 + (tid >> 6);
  int d = task >> 7, bct = task & 127;
  int bc0 = bct * 16;
  int pl = lane & 15, qh = lane >> 4;
  half8 az[4];
  const f16* zp = Z16 + ((size_t)d * 2048 + bc0 + pl) * 128 + qh * 8;
#pragma unroll
  for (int kt = 0; kt < 4; kt++) az[kt] = *(const half8*)(zp + kt * 32);
#pragma unroll
  for (int nt = 0; nt < 2; nt++) {
    f32x4 acc = f32x4{0.f, 0.f, 0.f, 0.f};
#pragma unroll
    for (int kt = 0; kt < 4; kt++)
      acc = __builtin_amdgcn_mfma_f32_16x16x32_f16(az[kt], WF[(size_t)d * 512 + (nt * 4 + kt) * 64 + lane], acc, 0, 0, 0);
#pragma unroll
    for (int r = 0; r < 4; r++)
      S16[((size_t)d * 2048 + bc0 + qh * 4 + r) * 32 + nt * 16 + pl] = (f16)acc[r];
  }
}

// -------- k_pass2: 3-phase block-local scan. grid 512 = (d,b); 256 thr = (g16, n16) --------
__global__ __launch_bounds__(256) void k_pass2(
    const f16* __restrict__ S16, const f32x2* __restrict__ LCLl,
    const f32x2* __restrict__ LC2Kl, f16* __restrict__ Sc) {
  __shared__ f32x2 gc[16][17];
  int blk = blockIdx.x;               // d*8 + b
  int d = blk >> 3, b = blk & 7;
  int t = threadIdx.x;                // g*16 + n
  int n = t & 15, g = t >> 4;
  f32x2 lam = LCLl[d * 16 + n];
  size_t base = ((size_t)d * 2048 + b * 256 + g * 16) * 32 + 2 * n;
  const f16* sp = S16 + base;
  float cr = 0.f, ci = 0.f;
#pragma unroll 4
  for (int j = 0; j < 16; j++) {
    half2t v = *(const half2t*)(sp + (size_t)j * 32);
    float nr = fmaf(lam.x, cr, fmaf(-lam.y, ci, (float)v[0]));
    float ni = fmaf(lam.x, ci, fmaf(lam.y, cr, (float)v[1]));
    cr = nr; ci = ni;
  }
  gc[g][n] = f32x2{cr, ci};
  __syncthreads();
  f32x2 l2 = LC2Kl[d * 16 + n];
  float er = 0.f, ei = 0.f;
  for (int gg = 0; gg < g; gg++) {
    f32x2 c = gc[gg][n];
    float nr = fmaf(l2.x, er, fmaf(-l2.y, ei, c.x));
    float ni = fmaf(l2.x, ei, fmaf(l2.y, er, c.y));
    er = nr; ei = ni;
  }
  f16* cp = Sc + base;
  float cr2 = er, ci2 = ei;
#pragma unroll 4
  for (int j = 0; j < 16; j++) {
    *(half2t*)(cp + (size_t)j * 32) = half2t{(f16)cr2, (f16)ci2};
    half2t v = *(const half2t*)(sp + (size_t)j * 32);
    float nr = fmaf(lam.x, cr2, fmaf(-lam.y, ci2, (float)v[0]));
    float ni = fmaf(lam.x, ci2, fmaf(lam.y, cr2, (float)v[1]));
    cr2 = nr; ci2 = ni;
  }
}

// -------- k_p3g2: y = T@z + V@carry, gelu -> Y16[pos][d]. mt-halved: grid 1024 --------
template <int NKT, int MT0>
__device__ __forceinline__ void p3g2_body(
    const f16* __restrict__ Z16, const f16* __restrict__ Sc,
    const half8* __restrict__ TF, const half8* __restrict__ VF,
    f16* __restrict__ Y16, int bc0, int dbase, int lane, int pl, int qh) {
  half8 zb[4][NKT];
  half8 sb[4];
#pragma unroll
  for (int di = 0; di < 4; di++) {
    int d = dbase + di;
    const f16* zp = Z16 + ((size_t)d * 2048 + bc0 + pl) * 128 + qh * 8;
#pragma unroll
    for (int kt = 0; kt < NKT; kt++) zb[di][kt] = *(const half8*)(zp + kt * 32);
    sb[di] = *(const half8*)(Sc + ((size_t)d * 2048 + bc0 + pl) * 32 + qh * 8);
  }
#pragma unroll
  for (int u = 0; u < 4; u++) {
    const int mt = MT0 + u;
    const int KTM = mt / 2 + 1;  // causal: tiles with ji0 <= jo_max
    f32x4 acc[4];
#pragma unroll
    for (int di = 0; di < 4; di++) {
      int d = dbase + di;
      acc[di] = f32x4{0.f, 0.f, 0.f, 0.f};
      const half8* tfp = TF + ((size_t)d * 8 + mt) * 256 + lane;
#pragma unroll
      for (int kt = 0; kt < KTM; kt++)
        acc[di] = __builtin_amdgcn_mfma_f32_16x16x32_f16(tfp[kt * 64], zb[di][kt], acc[di], 0, 0, 0);
      acc[di] = __builtin_amdgcn_mfma_f32_16x16x32_f16(VF[((size_t)d * 8 + mt) * 64 + lane], sb[di], acc[di], 0, 0, 0);
    }
#pragma unroll
    for (int r = 0; r < 4; r++) {
      int pos = (bc0 + pl) * 128 + mt * 16 + qh * 4 + r;
      half4 pk = half4{(f16)gelu_t(acc[0][r]), (f16)gelu_t(acc[1][r]),
                       (f16)gelu_t(acc[2][r]), (f16)gelu_t(acc[3][r])};
      *(half4*)(Y16 + (size_t)pos * 64 + dbase) = pk;
    }
  }
}

__global__ __launch_bounds__(256) void k_p3g2(
    const f16* __restrict__ Z16, const f16* __restrict__ Sc,
    const half8* __restrict__ TF, const half8* __restrict__ VF,
    f16* __restrict__ Y16) {
  int tid = threadIdx.x;
  int lane = tid & 63, widx = tid >> 6;
  int blk = blockIdx.x;               // grid 1024: (half, dg, bct)
  int half = blk >> 9, dg = (blk >> 7) & 3, bct = blk & 127;
  int bc0 = bct * 16;
  int dbase = dg * 16 + widx * 4;
  int pl = lane & 15, qh = lane >> 4;
  if (half == 0)
    p3g2_body<2, 0>(Z16, Sc, TF, VF, Y16, bc0, dbase, lane, pl, qh);
  else
    p3g2_body<4, 4>(Z16, Sc, TF, VF, Y16, bc0, dbase, lane, pl, qh);
}

// ======== Fused GLU+FF(+next-layer z | +head); 1024-thr blocks, 2 blocks/CU = 8 waves/SIMD ====
// LDS: sWg half8[1024]@0, sW1@16384, sW2@32768, floats[576]@49152,
//      ztile f16[64][132]@51456 (two 8-wave sub-phases) | sWf+headF (WZ=0). Total 68352.
template <int WZ>
__global__ __launch_bounds__(1024, 8) void k_gluff4(
    const f16* __restrict__ Y16, const float* __restrict__ Wg, const float* __restrict__ bg,
    const float* __restrict__ W1, const float* __restrict__ b1,
    const float* __restrict__ W2, const float* __restrict__ b2,
    const float* __restrict__ lnw, const float* __restrict__ lnb,
    const float* __restrict__ nlnw, const float* __restrict__ nlnb,
    f16* __restrict__ X, f16* __restrict__ Z16,
    const float* __restrict__ Wf, const float* __restrict__ bfb,
    const float* __restrict__ wz, const float* __restrict__ bz,
    float* __restrict__ outp) {
  __shared__ __align__(16) char smem[68352];
  int tid = threadIdx.x;
  {                                          // sWg: NATURAL k (1024 slots, 1 pass)
    int s = tid;
    int l = s & 63, ks = (s >> 6) & 1, et = s >> 7;
    const float* wp = Wg + (et * 16 + (l & 15)) * 64 + ks * 32 + (l >> 4) * 8;
    f32x4 w0 = *(const f32x4*)wp, w1 = *(const f32x4*)(wp + 4);
    *(half8*)(smem + s * 16) = half8{(f16)w0[0], (f16)w0[1], (f16)w0[2], (f16)w0[3],
                                     (f16)w1[0], (f16)w1[1], (f16)w1[2], (f16)w1[3]};
  }
  {                                          // sW1: PERMUTED k
    int s = tid;
    int l = s & 63, ks = (s >> 6) & 1, et = s >> 7;
    int pls = l & 15, qhs = l >> 4;
    const float* wp = W1 + (et * 16 + pls) * 64 + ks * 32 + qhs * 4;
    f32x4 w0 = *(const f32x4*)wp;
    f32x4 w1 = *(const f32x4*)(wp + 16);
    *(half8*)(smem + 16384 + s * 16) = half8{(f16)w0[0], (f16)w0[1], (f16)w0[2], (f16)w0[3],
                                             (f16)w1[0], (f16)w1[1], (f16)w1[2], (f16)w1[3]};
  }
  {                                          // sW2: PERMUTED k
    int s = tid;
    int l = s & 63, ks = (s >> 6) & 3, dt = s >> 8;
    int pls = l & 15, qhs = l >> 4;
    const float* wp = W2 + (dt * 16 + pls) * 128 + ks * 32 + qhs * 4;
    f32x4 w0 = *(const f32x4*)wp;
    f32x4 w1 = *(const f32x4*)(wp + 16);
    *(half8*)(smem + 32768 + s * 16) = half8{(f16)w0[0], (f16)w0[1], (f16)w0[2], (f16)w0[3],
                                             (f16)w1[0], (f16)w1[1], (f16)w1[2], (f16)w1[3]};
  }
  if (tid < 576) {
    int idx = tid;
    float v;
    if (idx < 128) v = bg[idx];
    else if (idx < 256) v = b1[idx - 128];
    else if (idx < 320) v = b2[idx - 256];
    else if (idx < 384) v = lnw[idx - 320];
    else if (idx < 448) v = lnb[idx - 384];
    else if (idx < 512) v = nlnw[idx - 448];
    else v = nlnb[idx - 512];
    ((float*)(smem + 49152))[idx] = v;
  }
  if constexpr (!WZ) {
    if (tid < 512) {                         // sWf: PERMUTED k (head GEMM)
      int s = tid;
      int l = s & 63, ks = (s >> 6) & 1, et = s >> 7;  // et < 4
      int pls = l & 15, qhs = l >> 4;
      const float* wp = Wf + (et * 16 + pls) * 64 + ks * 32 + qhs * 4;
      f32x4 w0 = *(const f32x4*)wp;
      f32x4 w1 = *(const f32x4*)(wp + 16);
      *(half8*)(smem + 51456 + s * 16) = half8{(f16)w0[0], (f16)w0[1], (f16)w0[2], (f16)w0[3],
                                               (f16)w1[0], (f16)w1[1], (f16)w1[2], (f16)w1[3]};
    }
    if (tid < 129) {
      float v = tid < 64 ? bfb[tid] : (tid < 128 ? wz[tid - 64] : bz[0]);
      ((float*)(smem + 59648))[tid] = v;
    }
  }
  __syncthreads();
  int lane = tid & 63, pl = lane & 15, qh = lane >> 4;
  int widx = tid >> 6;                       // 0..15
  f16* ztile = (f16*)(smem + 51456);

  for (int k = 0; k < 2; ++k) {
    int pt = blockIdx.x * 16 + widx + k * 8192;
    int pos = pt * 16 + pl;
    half8 yb0 = *(const half8*)(Y16 + (size_t)pos * 64 + qh * 8);
    half8 yb1 = *(const half8*)(Y16 + (size_t)pos * 64 + 32 + qh * 8);
    f32x4 xv[4];
#pragma unroll
    for (int q = 0; q < 4; q++) {
      half4 xh = *(const half4*)(X + (size_t)pos * 64 + q * 16 + qh * 4);
#pragma unroll
      for (int r = 0; r < 4; r++) xv[q][r] = (float)xh[r];
    }

    unsigned sb = 0;
    asm volatile("" : "+v"(sb));                // opaque: defeats LICM (anti-spill, R4-proven)
    const char* sm = smem + sb;
    const half8* sWg = (const half8*)sm;
    const half8* sW1 = (const half8*)(sm + 16384);
    const half8* sW2 = (const half8*)(sm + 32768);
    const float* sf = (const float*)(sm + 49152);
    // ---- GLU ----
    f32x4 accg[8];
#pragma unroll
    for (int et = 0; et < 8; et++) accg[et] = *(const f32x4*)(sf + et * 16 + qh * 4);
#pragma unroll
    for (int et = 0; et < 8; et++)
      accg[et] = __builtin_amdgcn_mfma_f32_16x16x32_f16(sWg[(et * 2) * 64 + lane], yb0, accg[et], 0, 0, 0);
#pragma unroll
    for (int et = 0; et < 8; et++)
      accg[et] = __builtin_amdgcn_mfma_f32_16x16x32_f16(sWg[(et * 2 + 1) * 64 + lane], yb1, accg[et], 0, 0, 0);
    float s = 0.f, s2 = 0.f;
#pragma unroll
    for (int q = 0; q < 4; q++)
#pragma unroll
      for (int r = 0; r < 4; r++) {
        xv[q][r] += accg[q][r] * sigm(accg[q + 4][r]);
        s += xv[q][r]; s2 += xv[q][r] * xv[q][r];
      }
    s += __shfl_xor(s, 16); s += __shfl_xor(s, 32);
    s2 += __shfl_xor(s2, 16); s2 += __shfl_xor(s2, 32);
    float m = s * (1.0f / 64.0f);
    float rstd = rsqrtf(s2 * (1.0f / 64.0f) - m * m + 1e-5f);
    // ---- FF GEMM1 (K=32 permuted frags) ----
    half4 zb4[4];
#pragma unroll
    for (int ks = 0; ks < 4; ks++) {
      f32x4 lw = *(const f32x4*)(sf + 320 + ks * 16 + qh * 4);
      f32x4 lb = *(const f32x4*)(sf + 384 + ks * 16 + qh * 4);
      half4 z;
#pragma unroll
      for (int r = 0; r < 4; r++) z[r] = (f16)fmaf((xv[ks][r] - m) * rstd, lw[r], lb[r]);
      zb4[ks] = z;
    }
    f32x4 acc1[8];
#pragma unroll
    for (int et = 0; et < 8; et++) acc1[et] = *(const f32x4*)(sf + 128 + et * 16 + qh * 4);
#pragma unroll
    for (int ks = 0; ks < 2; ks++) {
      half4 a = zb4[ks * 2], b = zb4[ks * 2 + 1];
      half8 zb8 = half8{a[0], a[1], a[2], a[3], b[0], b[1], b[2], b[3]};
#pragma unroll
      for (int et = 0; et < 8; et++)
        acc1[et] = __builtin_amdgcn_mfma_f32_16x16x32_f16(sW1[(et * 2 + ks) * 64 + lane], zb8, acc1[et], 0, 0, 0);
    }
    half4 h4[8];
#pragma unroll
    for (int et = 0; et < 8; et++)
      h4[et] = half4{(f16)gelu_t(acc1[et][0]), (f16)gelu_t(acc1[et][1]),
                     (f16)gelu_t(acc1[et][2]), (f16)gelu_t(acc1[et][3])};
    // ---- FF GEMM2 (K=128 as 4x32 permuted frags) ----
    f32x4 acc2[4];
#pragma unroll
    for (int dt = 0; dt < 4; dt++) acc2[dt] = *(const f32x4*)(sf + 256 + dt * 16 + qh * 4);
#pragma unroll
    for (int ks = 0; ks < 4; ks++) {
      half4 a = h4[ks * 2], b = h4[ks * 2 + 1];
      half8 hb8 = half8{a[0], a[1], a[2], a[3], b[0], b[1], b[2], b[3]};
#pragma unroll
      for (int dt = 0; dt < 4; dt++)
        acc2[dt] = __builtin_amdgcn_mfma_f32_16x16x32_f16(sW2[(dt * 4 + ks) * 64 + lane], hb8, acc2[dt], 0, 0, 0);
    }
    s = 0.f; s2 = 0.f;
#pragma unroll
    for (int dt = 0; dt < 4; dt++) {
#pragma unroll
      for (int r = 0; r < 4; r++) {
        xv[dt][r] += acc2[dt][r];
        s += xv[dt][r]; s2 += xv[dt][r] * xv[dt][r];
      }
      if constexpr (WZ) {
        half4 xo = half4{(f16)xv[dt][0], (f16)xv[dt][1], (f16)xv[dt][2], (f16)xv[dt][3]};
        *(half4*)(X + (size_t)pos * 64 + dt * 16 + qh * 4) = xo;
      }
    }
    s += __shfl_xor(s, 16); s += __shfl_xor(s, 32);
    s2 += __shfl_xor(s2, 16); s2 += __shfl_xor(s2, 32);
    float m2 = s * (1.0f / 64.0f);
    float rstd2 = rsqrtf(s2 * (1.0f / 64.0f) - m2 * m2 + 1e-5f);

    if constexpr (WZ) {
      // next-layer s4-LN z in registers, then two 8-wave LDS-transpose sub-phases
      half4 zreg[4];
#pragma unroll
      for (int q = 0; q < 4; q++) {
        int d0 = q * 16 + qh * 4;
        f32x4 lw = *(const f32x4*)(sf + 448 + d0);
        f32x4 lb = *(const f32x4*)(sf + 512 + d0);
        half4 z;
#pragma unroll
        for (int r = 0; r < 4; r++) z[r] = (f16)fmaf((xv[q][r] - m2) * rstd2, lw[r], lb[r]);
        zreg[q] = z;
      }
      size_t baseA = (size_t)blockIdx.x * 256 + (size_t)k * 131072;
      if (widx < 8) {
        int prow = widx * 16 + pl;
#pragma unroll
        for (int q = 0; q < 4; q++) {
          int d0 = q * 16 + qh * 4;
#pragma unroll
          for (int r = 0; r < 4; r++) ztile[(d0 + r) * 132 + prow] = zreg[q][r];
        }
      }
      __syncthreads();
      {
        int d = tid >> 4, c0 = (tid & 15) * 8;
        half8 z0 = *(const half8*)(ztile + d * 132 + c0);
        *(half8*)(Z16 + (size_t)d * 262144 + baseA + c0) = z0;
      }
      __syncthreads();
      if (widx >= 8) {
        int prow = (widx - 8) * 16 + pl;
#pragma unroll
        for (int q = 0; q < 4; q++) {
          int d0 = q * 16 + qh * 4;
#pragma unroll
          for (int r = 0; r < 4; r++) ztile[(d0 + r) * 132 + prow] = zreg[q][r];
        }
      }
      __syncthreads();
      {
        int d = tid >> 4, c0 = (tid & 15) * 8;
        half8 z0 = *(const half8*)(ztile + d * 132 + c0);
        *(half8*)(Z16 + (size_t)d * 262144 + baseA + 128 + c0) = z0;
      }
      __syncthreads();
    } else {
      // ---- fused head: z = normLN(x); u = Wf z + bfb; o = wz . relu(u) + bz ----
      const half8* sWf = (const half8*)(sm + 51456);
      const float* hf = (const float*)(sm + 59648);
      half4 hz[4];
#pragma unroll
      for (int ks = 0; ks < 4; ks++) {
        f32x4 lw = *(const f32x4*)(sf + 448 + ks * 16 + qh * 4);
        f32x4 lb = *(const f32x4*)(sf + 512 + ks * 16 + qh * 4);
        half4 z;
#pragma unroll
        for (int r = 0; r < 4; r++) z[r] = (f16)fmaf((xv[ks][r] - m2) * rstd2, lw[r], lb[r]);
        hz[ks] = z;
      }
      f32x4 acch[4];
#pragma unroll
      for (int et = 0; et < 4; et++) acch[et] = *(const f32x4*)(hf + et * 16 + qh * 4);
#pragma unroll
      for (int ks = 0; ks < 2; ks++) {
        half4 a = hz[ks * 2], b = hz[ks * 2 + 1];
        half8 zb8 = half8{a[0], a[1], a[2], a[3], b[0], b[1], b[2], b[3]};
#pragma unroll
        for (int et = 0; et < 4; et++)
          acch[et] = __builtin_amdgcn_mfma_f32_16x16x32_f16(sWf[(et * 2 + ks) * 64 + lane], zb8, acch[et], 0, 0, 0);
      }
      float o = 0.f;
#pragma unroll
      for (int et = 0; et < 4; et++) {
        f32x4 wzv = *(const f32x4*)(hf + 64 + et * 16 + qh * 4);
#pragma unroll
        for (int r = 0; r < 4; r++) {
          float rv = acch[et][r];
          rv = rv > 0.f ? rv : 0.f;
          o = fmaf(wzv[r], rv, o);
        }
      }
      o += __shfl_xor(o, 16); o += __shfl_xor(o, 32);
      if (qh == 0) outp[pos] = o + hf[128];
    }
  }
}

extern "C" void kernel_launch(void* const* d_in, const int* in_sizes, int n_in,
                              void* d_out, int out_size, void* d_ws, size_t ws_size,
                              hipStream_t stream) {
  (void)in_sizes; (void)n_in; (void)out_size; (void)ws_size;
  const float* inputs   = (const float*)d_in[0];
  const float* w_init   = (const float*)d_in[1];
  const float* b_init   = (const float*)d_in[2];
  const float* s4_ln_w  = (const float*)d_in[3];
  const float* s4_ln_b  = (const float*)d_in[4];
  const float* log_dt   = (const float*)d_in[5];
  const float* log_A    = (const float*)d_in[6];
  const float* A_imag   = (const float*)d_in[7];
  const float* C_re     = (const float*)d_in[8];
  const float* C_im     = (const float*)d_in[9];
  const float* D_skip   = (const float*)d_in[10];
  const float* s4_out_w = (const float*)d_in[11];
  const float* s4_out_b = (const float*)d_in[12];
  const float* ff_ln_w  = (const float*)d_in[13];
  const float* ff_ln_b  = (const float*)d_in[14];
  const float* ff_w1    = (const float*)d_in[15];
  const float* ff_b1    = (const float*)d_in[16];
  const float* ff_w2    = (const float*)d_in[17];
  const float* ff_b2    = (const float*)d_in[18];
  const float* norm_w   = (const float*)d_in[19];
  const float* norm_b   = (const float*)d_in[20];
  const float* w_final1 = (const float*)d_in[21];
  const float* b_final1 = (const float*)d_in[22];
  const float* w_zero   = (const float*)d_in[23];
  const float* b_zero   = (const float*)d_in[24];

  char* w8 = (char*)d_ws;
  size_t off = 0;
  f16*   X     = (f16*)(w8 + off);   off += (size_t)33554432;   // [pos][64] f16
  f16*   Z16   = (f16*)(w8 + off);   off += (size_t)33554432;   // [d][pos] f16
  f16*   Y16   = (f16*)(w8 + off);   off += (size_t)33554432;   // [pos][d] f16
  f16*   S16   = (f16*)(w8 + off);   off += (size_t)8388608;    // [d][bc][32] f16
  f16*   Sc    = (f16*)(w8 + off);   off += (size_t)8388608;    // [d][bc][32] f16
  f32x2* LCL   = (f32x2*)(w8 + off); off += 32768;
  f32x2* LC2K  = (f32x2*)(w8 + off); off += 32768;
  half8* TF    = (half8*)(w8 + off); off += (size_t)8388608;    // 4 layers x 2MB
  half8* VF    = (half8*)(w8 + off); off += (size_t)2097152;
  half8* WF    = (half8*)(w8 + off); off += (size_t)2097152;

  k_wtall<<<256, 128, 0, stream>>>(log_dt, log_A, A_imag, C_re, C_im, D_skip,
                                   LCL, LC2K, TF, VF, WF);
  k_init3<<<512, 512, 0, stream>>>(inputs, w_init, b_init, s4_ln_w, s4_ln_b, X, Z16);
  for (int i = 0; i < NLq; i++) {
    k_p1g<<<2048, 256, 0, stream>>>(Z16, WF + (size_t)i * 32768, S16);
    k_pass2<<<512, 256, 0, stream>>>(S16, LCL + i * 1024, LC2K + i * 1024, Sc);
    k_p3g2<<<1024, 256, 0, stream>>>(Z16, Sc, TF + (size_t)i * 131072, VF + (size_t)i * 32768, Y16);
    if (i < NLq - 1) {
      k_gluff4<1><<<512, 1024, 0, stream>>>(Y16, s4_out_w + i * 8192, s4_out_b + i * 128,
                                            ff_w1 + i * 8192, ff_b1 + i * 128,
                                            ff_w2 + i * 8192, ff_b2 + i * 64,
                                            ff_ln_w + i * 64, ff_ln_b + i * 64,
                                            s4_ln_w + (i + 1) * 64, s4_ln_b + (i + 1) * 64,
                                            X, Z16, nullptr, nullptr, nullptr, nullptr, nullptr);
    } else {
      k_gluff4<0><<<512, 1024, 0, stream>>>(Y16, s4_out_w + i * 8192, s4_out_b + i * 128,
                                            ff_w1 + i * 8192, ff_b1 + i * 128,
                                            ff_w2 + i * 8192, ff_b2 + i * 64,
                                            ff_ln_w + i * 64, ff_ln_b + i * 64,
                                            norm_w, norm_b,
                                            X, Z16, w_final1, b_final1, w_zero, b_zero,
                                            (float*)d_out);
    }
  }
}

// Round 13
// 509.491 us; speedup vs baseline: 1.0571x; 1.0571x over previous
//
#include <hip/hip_runtime.h>
#include <cmath>

constexpr int Bq = 8, Lq = 32768, Dq = 64, Nq = 16, NLq = 4;
constexpr int CLq = 128, NCq = 256;           // NCq*CLq == Lq ; chunks per batch
constexpr int PT = Bq * Lq / 16;              // 16384 position-tiles of 16

typedef _Float16 f16;
typedef _Float16 half2t __attribute__((ext_vector_type(2)));
typedef _Float16 half4 __attribute__((ext_vector_type(4)));
typedef _Float16 half8 __attribute__((ext_vector_type(8)));
typedef float f32x4 __attribute__((ext_vector_type(4)));
typedef float f32x2 __attribute__((ext_vector_type(2)));

static __device__ __forceinline__ float sigm(float x) { return 1.0f / (1.0f + __expf(-x)); }
static __device__ __forceinline__ float gelu_t(float x) {
  return x * sigm(1.5957691216057308f * fmaf(0.044715f * x * x, x, x));
}

// -------- k_wtall: setup + all layers' frag-ordered f16 matrices TF/VF/WF; LCL, LC2K --------
__global__ __launch_bounds__(128) void k_wtall(
    const float* __restrict__ log_dt, const float* __restrict__ log_A_real,
    const float* __restrict__ A_imag, const float* __restrict__ C_re,
    const float* __restrict__ C_im, const float* __restrict__ dskip,
    f32x2* __restrict__ LCL, f32x2* __restrict__ LC2K, half8* __restrict__ TF,
    half8* __restrict__ VF, half8* __restrict__ WF) {
  __shared__ f32x2 pw[129][16];
  __shared__ f32x2 lamS[16], dcS[16];
  __shared__ float Ks[128];
  int d = blockIdx.x & 63, L = blockIdx.x >> 6;
  half8* TFl = TF + (size_t)L * 131072;
  half8* VFl = VF + (size_t)L * 32768;
  half8* WFl = WF + (size_t)L * 32768;
  int t = threadIdx.x;
  if (t < 16) {
    int di = L * 64 + d;
    int idx = di * 16 + t;
    float dt = expf(log_dt[di]);
    float Ar = -expf(log_A_real[idx]);
    float Ai = A_imag[idx];
    float dr = Ar * dt, dmi = Ai * dt;
    float er = expf(dr);
    float lr = er * cosf(dmi), li = er * sinf(dmi);
    float inv = 1.0f / (Ar * Ar + Ai * Ai);
    float e1r = lr - 1.0f, e1i = li;
    float qr = (e1r * Ar + e1i * Ai) * inv;
    float qi = (e1i * Ar - e1r * Ai) * inv;
    float cr = C_re[idx], ci = C_im[idx];
    lamS[t] = f32x2{lr, li};
    dcS[t] = f32x2{2.0f * (cr * qr - ci * qi), 2.0f * (cr * qi + ci * qr)};
    float erc = expf(dr * 128.0f);
    f32x2 l128 = f32x2{erc * cosf(dmi * 128.0f), erc * sinf(dmi * 128.0f)};
    pw[128][t] = l128;
    LCL[(size_t)L * 1024 + d * 16 + t] = l128;
    float br = l128.x, bi = l128.y;
#pragma unroll
    for (int q = 0; q < 4; q++) {
      float t2 = br * br - bi * bi;
      bi = 2.f * br * bi; br = t2;
    }
    LC2K[(size_t)L * 1024 + d * 16 + t] = f32x2{br, bi};
  }
  __syncthreads();
#pragma unroll
  for (int n = 0; n < 16; n++) {
    f32x2 lam = lamS[n];
    float pr = 1.f, pi = 0.f, br = lam.x, bi = lam.y;
    int e = t;
    while (e) {
      if (e & 1) { float tt = pr * br - pi * bi; pi = fmaf(pr, bi, pi * br); pr = tt; }
      float t2 = br * br - bi * bi; bi = 2.f * br * bi; br = t2; e >>= 1;
    }
    pw[t][n] = f32x2{pr, pi};
  }
  __syncthreads();
  {
    float k = 0.f;
#pragma unroll
    for (int n = 0; n < 16; n++) {
      f32x2 dc = dcS[n];
      f32x2 p = pw[t][n];
      k += dc.x * p.x - dc.y * p.y;
    }
    if (t == 0) k += dskip[L * 64 + d];
    Ks[t] = k;
  }
  __syncthreads();
  for (int s = t; s < 2048; s += 128) {
    int ln = s & 63, kt = (s >> 6) & 3, mt = s >> 8;
    int jo = mt * 16 + (ln & 15);
    int ji0 = kt * 32 + (ln >> 4) * 8;
    half8 v;
#pragma unroll
    for (int jj = 0; jj < 8; jj++) {
      int ji = ji0 + jj;
      v[jj] = (jo >= ji) ? (f16)Ks[jo - ji] : (f16)0.f;
    }
    TFl[(size_t)d * 2048 + s] = v;
  }
  for (int s = t; s < 512; s += 128) {
    int ln = s & 63, mt = s >> 6;
    int jo = mt * 16 + (ln & 15);
    int q0 = (ln >> 4) * 8;
    half8 v;
#pragma unroll
    for (int jj = 0; jj < 8; jj++) {
      int q = q0 + jj, n = q >> 1;
      f32x2 dc = dcS[n];
      f32x2 p = pw[jo + 1][n];
      float wr = dc.x * p.x - dc.y * p.y;
      float wi = dc.x * p.y + dc.y * p.x;
      v[jj] = (q & 1) ? (f16)(-wi) : (f16)wr;
    }
    VFl[(size_t)d * 512 + s] = v;
  }
  for (int s = t; s < 512; s += 128) {
    int ln = s & 63, kt = (s >> 6) & 3, nt = s >> 8;
    int p_ = nt * 16 + (ln & 15);
    int n = p_ >> 1;
    int j0 = kt * 32 + (ln >> 4) * 8;
    half8 v;
#pragma unroll
    for (int jj = 0; jj < 8; jj++) {
      f32x2 p = pw[127 - (j0 + jj)][n];
      v[jj] = (p_ & 1) ? (f16)p.y : (f16)p.x;
    }
    WFl[(size_t)d * 512 + s] = v;
  }
}

// -------- k_wprep: frag-order ff_w2 (PERMUTED k) into f16 W2F[4][1024] --------
__global__ __launch_bounds__(256) void k_wprep(
    const float* __restrict__ W2all, half8* __restrict__ W2F) {
  int L = blockIdx.x;
  const float* W2 = W2all + L * 8192;
  half8* out = W2F + (size_t)L * 1024;
  int tid = threadIdx.x;
#pragma unroll
  for (int it = 0; it < 4; it++) {
    int s = it * 256 + tid;
    int l = s & 63, ks = (s >> 6) & 3, dt = s >> 8;
    int pls = l & 15, qhs = l >> 4;
    const float* wp = W2 + (dt * 16 + pls) * 128 + ks * 32 + qhs * 4;
    f32x4 w0 = *(const f32x4*)wp;
    f32x4 w1 = *(const f32x4*)(wp + 16);
    out[s] = half8{(f16)w0[0], (f16)w0[1], (f16)w0[2], (f16)w0[3],
                   (f16)w1[0], (f16)w1[1], (f16)w1[2], (f16)w1[3]};
  }
}

// -------- k_init3: x = relu(w_init*in + b_init) -> X f16; z = s4LN0(x) -> Z16 --------
__global__ __launch_bounds__(512) void k_init3(
    const float* __restrict__ inp, const float* __restrict__ w_init,
    const float* __restrict__ b_init, const float* __restrict__ lnw,
    const float* __restrict__ lnb, f16* __restrict__ X, f16* __restrict__ Z16) {
  __shared__ __align__(16) f16 ztile[64 * 132];
  int tid = threadIdx.x;
  int widx = tid >> 6, lane = tid & 63;
  int pl = lane & 15, qh = lane >> 4;
  for (int k = 0; k < 4; ++k) {
    int pt = blockIdx.x * 8 + widx + k * 4096;
    int pos = pt * 16 + pl;
    float v = inp[pos];
    float s = 0.f, s2 = 0.f;
    f32x4 o[4];
#pragma unroll
    for (int q = 0; q < 4; q++) {
      int d0 = q * 16 + qh * 4;
      f32x4 w4 = *(const f32x4*)(w_init + d0);
      f32x4 b4 = *(const f32x4*)(b_init + d0);
#pragma unroll
      for (int j = 0; j < 4; j++) {
        float t = fmaf(w4[j], v, b4[j]);
        t = t > 0.f ? t : 0.f;
        o[q][j] = t; s += t; s2 += t * t;
      }
      half4 xo = half4{(f16)o[q][0], (f16)o[q][1], (f16)o[q][2], (f16)o[q][3]};
      *(half4*)(X + (size_t)pos * 64 + d0) = xo;
    }
    s += __shfl_xor(s, 16); s += __shfl_xor(s, 32);
    s2 += __shfl_xor(s2, 16); s2 += __shfl_xor(s2, 32);
    float m = s * (1.0f / 64.0f);
    float rstd = rsqrtf(s2 * (1.0f / 64.0f) - m * m + 1e-5f);
    int prow = widx * 16 + pl;
#pragma unroll
    for (int q = 0; q < 4; q++) {
      int d0 = q * 16 + qh * 4;
      f32x4 lw = *(const f32x4*)(lnw + d0);
      f32x4 lb = *(const f32x4*)(lnb + d0);
#pragma unroll
      for (int r = 0; r < 4; r++)
        ztile[(d0 + r) * 132 + prow] = (f16)fmaf((o[q][r] - m) * rstd, lw[r], lb[r]);
    }
    __syncthreads();
    {
      int d = tid >> 3, c0 = (tid & 7) * 16;
      half8 z0 = *(const half8*)(ztile + d * 132 + c0);
      half8 z1 = *(const half8*)(ztile + d * 132 + c0 + 8);
      size_t zoff = (size_t)d * 262144 + (size_t)(blockIdx.x * 8 + k * 4096) * 16;
      *(half8*)(Z16 + zoff + c0) = z0;
      *(half8*)(Z16 + zoff + c0 + 8) = z1;
    }
    __syncthreads();
  }
}

// -------- k_p1g: chunk end-states S16[d][bc][p32] = Z(m=bc,k=j) @ Wend(k=j,n=p) --------
__global__ __launch_bounds__(256) void k_p1g(
    const f16* __restrict__ Z16, const half8* __restrict__ WF, f16* __restrict__ S16) {
  int tid = threadIdx.x;
  int lane = tid & 63;
  int task = blockIdx.x * 4 + (tid >> 6);
  int d = task >> 7, bct = task & 127;
  int bc0 = bct * 16;
  int pl = lane & 15, qh = lane >> 4;
  half8 az[4];
  const f16* zp = Z16 + ((size_t)d * 2048 + bc0 + pl) * 128 + qh * 8;
#pragma unroll
  for (int kt = 0; kt < 4; kt++) az[kt] = *(const half8*)(zp + kt * 32);
#pragma unroll
  for (int nt = 0; nt < 2; nt++) {
    f32x4 acc = f32x4{0.f, 0.f, 0.f, 0.f};
#pragma unroll
    for (int kt = 0; kt < 4; kt++)
      acc = __builtin_amdgcn_mfma_f32_16x16x32_f16(az[kt], WF[(size_t)d * 512 + (nt * 4 + kt) * 64 + lane], acc, 0, 0, 0);
#pragma unroll
    for (int r = 0; r < 4; r++)
      S16[((size_t)d * 2048 + bc0 + qh * 4 + r) * 32 + nt * 16 + pl] = (f16)acc[r];
  }
}

// -------- k_pass2: 3-phase block-local scan. grid 512 = (d,b); 256 thr = (g16, n16) --------
__global__ __launch_bounds__(256) void k_pass2(
    const f16* __restrict__ S16, const f32x2* __restrict__ LCLl,
    const f32x2* __restrict__ LC2Kl, f16* __restrict__ Sc) {
  __shared__ f32x2 gc[16][17];
  int blk = blockIdx.x;               // d*8 + b
  int d = blk >> 3, b = blk & 7;
  int t = threadIdx.x;                // g*16 + n
  int n = t & 15, g = t >> 4;
  f32x2 lam = LCLl[d * 16 + n];
  size_t base = ((size_t)d * 2048 + b * 256 + g * 16) * 32 + 2 * n;
  const f16* sp = S16 + base;
  float cr = 0.f, ci = 0.f;
#pragma unroll 4
  for (int j = 0; j < 16; j++) {
    half2t v = *(const half2t*)(sp + (size_t)j * 32);
    float nr = fmaf(lam.x, cr, fmaf(-lam.y, ci, (float)v[0]));
    float ni = fmaf(lam.x, ci, fmaf(lam.y, cr, (float)v[1]));
    cr = nr; ci = ni;
  }
  gc[g][n] = f32x2{cr, ci};
  __syncthreads();
  f32x2 l2 = LC2Kl[d * 16 + n];
  float er = 0.f, ei = 0.f;
  for (int gg = 0; gg < g; gg++) {
    f32x2 c = gc[gg][n];
    float nr = fmaf(l2.x, er, fmaf(-l2.y, ei, c.x));
    float ni = fmaf(l2.x, ei, fmaf(l2.y, er, c.y));
    er = nr; ei = ni;
  }
  f16* cp = Sc + base;
  float cr2 = er, ci2 = ei;
#pragma unroll 4
  for (int j = 0; j < 16; j++) {
    *(half2t*)(cp + (size_t)j * 32) = half2t{(f16)cr2, (f16)ci2};
    half2t v = *(const half2t*)(sp + (size_t)j * 32);
    float nr = fmaf(lam.x, cr2, fmaf(-lam.y, ci2, (float)v[0]));
    float ni = fmaf(lam.x, ci2, fmaf(lam.y, cr2, (float)v[1]));
    cr2 = nr; ci2 = ni;
  }
}

// -------- k_p3g2: y = T@z + V@carry, gelu -> Y16[pos][d] (d-packed half4), grid 512 --------
__global__ __launch_bounds__(256) void k_p3g2(
    const f16* __restrict__ Z16, const f16* __restrict__ Sc,
    const half8* __restrict__ TF, const half8* __restrict__ VF,
    f16* __restrict__ Y16) {
  int tid = threadIdx.x;
  int lane = tid & 63, widx = tid >> 6;
  int bct = blockIdx.x & 127, dg = blockIdx.x >> 7;  // grid 512: 4 dg x 128 bct
  int bc0 = bct * 16;
  int dbase = dg * 16 + widx * 4;
  int pl = lane & 15, qh = lane >> 4;
  half8 zb[4][4];
  half8 sb[4];
#pragma unroll
  for (int di = 0; di < 4; di++) {
    int d = dbase + di;
    const f16* zp = Z16 + ((size_t)d * 2048 + bc0 + pl) * 128 + qh * 8;
#pragma unroll
    for (int kt = 0; kt < 4; kt++) zb[di][kt] = *(const half8*)(zp + kt * 32);
    sb[di] = *(const half8*)(Sc + ((size_t)d * 2048 + bc0 + pl) * 32 + qh * 8);
  }
#pragma unroll
  for (int mt = 0; mt < 8; mt++) {
    const int KTM = mt / 2 + 1;  // causal: tiles with ji0 <= jo_max
    f32x4 acc[4];
#pragma unroll
    for (int di = 0; di < 4; di++) {
      int d = dbase + di;
      acc[di] = f32x4{0.f, 0.f, 0.f, 0.f};
      const half8* tfp = TF + ((size_t)d * 8 + mt) * 256 + lane;
#pragma unroll
      for (int kt = 0; kt < KTM; kt++)
        acc[di] = __builtin_amdgcn_mfma_f32_16x16x32_f16(tfp[kt * 64], zb[di][kt], acc[di], 0, 0, 0);
      acc[di] = __builtin_amdgcn_mfma_f32_16x16x32_f16(VF[((size_t)d * 8 + mt) * 64 + lane], sb[di], acc[di], 0, 0, 0);
    }
#pragma unroll
    for (int r = 0; r < 4; r++) {
      int pos = (bc0 + pl) * 128 + mt * 16 + qh * 4 + r;
      half4 pk = half4{(f16)gelu_t(acc[0][r]), (f16)gelu_t(acc[1][r]),
                       (f16)gelu_t(acc[2][r]), (f16)gelu_t(acc[3][r])};
      *(half4*)(Y16 + (size_t)pos * 64 + dbase) = pk;
    }
  }
}

// ======== Fused GLU+FF(+next-layer z | +head); W2 frags from global (L2), 3 blocks/CU ========
// LDS: sWg half8[1024]@0, sW1 half8[1024]@16384, floats[576]@32768,
//      ztile f16[64][132]@35072 (WZ=1) | sWf half8[512]@35072 + headF[129]@43264 (WZ=0).
// Total 51968 -> 3 blocks/CU at 512 thr = 6 waves/SIMD. VGPR cap 84 via launch_bounds(512,6).
template <int WZ>
__global__ __launch_bounds__(512, 6) void k_gluff5(
    const f16* __restrict__ Y16, const float* __restrict__ Wg, const float* __restrict__ bg,
    const float* __restrict__ W1, const float* __restrict__ b1,
    const half8* __restrict__ W2F, const float* __restrict__ b2,
    const float* __restrict__ lnw, const float* __restrict__ lnb,
    const float* __restrict__ nlnw, const float* __restrict__ nlnb,
    f16* __restrict__ X, f16* __restrict__ Z16,
    const float* __restrict__ Wf, const float* __restrict__ bfb,
    const float* __restrict__ wz, const float* __restrict__ bz,
    float* __restrict__ outp) {
  __shared__ __align__(16) char smem[51968];
  int tid = threadIdx.x;
#pragma unroll
  for (int it = 0; it < 2; it++) {           // sWg: NATURAL k
    int s = it * 512 + tid;
    int l = s & 63, ks = (s >> 6) & 1, et = s >> 7;
    const float* wp = Wg + (et * 16 + (l & 15)) * 64 + ks * 32 + (l >> 4) * 8;
    f32x4 w0 = *(const f32x4*)wp, w1 = *(const f32x4*)(wp + 4);
    *(half8*)(smem + s * 16) = half8{(f16)w0[0], (f16)w0[1], (f16)w0[2], (f16)w0[3],
                                     (f16)w1[0], (f16)w1[1], (f16)w1[2], (f16)w1[3]};
  }
#pragma unroll
  for (int it = 0; it < 2; it++) {           // sW1: PERMUTED k
    int s = it * 512 + tid;
    int l = s & 63, ks = (s >> 6) & 1, et = s >> 7;
    int pls = l & 15, qhs = l >> 4;
    const float* wp = W1 + (et * 16 + pls) * 64 + ks * 32 + qhs * 4;
    f32x4 w0 = *(const f32x4*)wp;
    f32x4 w1 = *(const f32x4*)(wp + 16);
    *(half8*)(smem + 16384 + s * 16) = half8{(f16)w0[0], (f16)w0[1], (f16)w0[2], (f16)w0[3],
                                             (f16)w1[0], (f16)w1[1], (f16)w1[2], (f16)w1[3]};
  }
  for (int idx = tid; idx < 576; idx += 512) {
    float v;
    if (idx < 128) v = bg[idx];
    else if (idx < 256) v = b1[idx - 128];
    else if (idx < 320) v = b2[idx - 256];
    else if (idx < 384) v = lnw[idx - 320];
    else if (idx < 448) v = lnb[idx - 384];
    else if (idx < 512) v = nlnw[idx - 448];
    else v = nlnb[idx - 512];
    ((float*)(smem + 32768))[idx] = v;
  }
  if constexpr (!WZ) {
    if (tid < 512) {                         // sWf: PERMUTED k (head GEMM)
      int s = tid;
      int l = s & 63, ks = (s >> 6) & 1, et = s >> 7;  // et < 4
      int pls = l & 15, qhs = l >> 4;
      const float* wp = Wf + (et * 16 + pls) * 64 + ks * 32 + qhs * 4;
      f32x4 w0 = *(const f32x4*)wp;
      f32x4 w1 = *(const f32x4*)(wp + 16);
      *(half8*)(smem + 35072 + s * 16) = half8{(f16)w0[0], (f16)w0[1], (f16)w0[2], (f16)w0[3],
                                               (f16)w1[0], (f16)w1[1], (f16)w1[2], (f16)w1[3]};
    }
    if (tid < 129) {
      float v = tid < 64 ? bfb[tid] : (tid < 128 ? wz[tid - 64] : bz[0]);
      ((float*)(smem + 43264))[tid] = v;
    }
  }
  __syncthreads();
  int lane = tid & 63, pl = lane & 15, qh = lane >> 4;
  int widx = tid >> 6;
  f16* ztile = (f16*)(smem + 35072);

  for (int pt0 = blockIdx.x * 8; pt0 < PT; pt0 += 6144) {   // grid 768, block-uniform rounds
    int pt = pt0 + widx;
    int pos = pt * 16 + pl;
    half8 yb0 = *(const half8*)(Y16 + (size_t)pos * 64 + qh * 8);
    half8 yb1 = *(const half8*)(Y16 + (size_t)pos * 64 + 32 + qh * 8);
    f32x4 xv[4];
#pragma unroll
    for (int q = 0; q < 4; q++) {
      half4 xh = *(const half4*)(X + (size_t)pos * 64 + q * 16 + qh * 4);
#pragma unroll
      for (int r = 0; r < 4; r++) xv[q][r] = (float)xh[r];
    }

    unsigned sb = 0, o2 = 0;
    asm volatile("" : "+v"(sb));                // opaque: defeats LICM on LDS (anti-spill)
    asm volatile("" : "+v"(o2));                // opaque: defeats LICM on W2F global frags
    const char* sm = smem + sb;
    const half8* sWg = (const half8*)sm;
    const half8* sW1 = (const half8*)(sm + 16384);
    const half8* sW2g = W2F + o2;
    const float* sf = (const float*)(sm + 32768);
    // ---- GLU ----
    f32x4 accg[8];
#pragma unroll
    for (int et = 0; et < 8; et++) accg[et] = *(const f32x4*)(sf + et * 16 + qh * 4);
#pragma unroll
    for (int et = 0; et < 8; et++)
      accg[et] = __builtin_amdgcn_mfma_f32_16x16x32_f16(sWg[(et * 2) * 64 + lane], yb0, accg[et], 0, 0, 0);
#pragma unroll
    for (int et = 0; et < 8; et++)
      accg[et] = __builtin_amdgcn_mfma_f32_16x16x32_f16(sWg[(et * 2 + 1) * 64 + lane], yb1, accg[et], 0, 0, 0);
    float s = 0.f, s2 = 0.f;
#pragma unroll
    for (int q = 0; q < 4; q++)
#pragma unroll
      for (int r = 0; r < 4; r++) {
        xv[q][r] += accg[q][r] * sigm(accg[q + 4][r]);
        s += xv[q][r]; s2 += xv[q][r] * xv[q][r];
      }
    s += __shfl_xor(s, 16); s += __shfl_xor(s, 32);
    s2 += __shfl_xor(s2, 16); s2 += __shfl_xor(s2, 32);
    float m = s * (1.0f / 64.0f);
    float rstd = rsqrtf(s2 * (1.0f / 64.0f) - m * m + 1e-5f);
    // ---- FF GEMM1 (K=32 permuted frags) ----
    half4 zb4[4];
#pragma unroll
    for (int ks = 0; ks < 4; ks++) {
      f32x4 lw = *(const f32x4*)(sf + 320 + ks * 16 + qh * 4);
      f32x4 lb = *(const f32x4*)(sf + 384 + ks * 16 + qh * 4);
      half4 z;
#pragma unroll
      for (int r = 0; r < 4; r++) z[r] = (f16)fmaf((xv[ks][r] - m) * rstd, lw[r], lb[r]);
      zb4[ks] = z;
    }
    f32x4 acc1[8];
#pragma unroll
    for (int et = 0; et < 8; et++) acc1[et] = *(const f32x4*)(sf + 128 + et * 16 + qh * 4);
#pragma unroll
    for (int ks = 0; ks < 2; ks++) {
      half4 a = zb4[ks * 2], b = zb4[ks * 2 + 1];
      half8 zb8 = half8{a[0], a[1], a[2], a[3], b[0], b[1], b[2], b[3]};
#pragma unroll
      for (int et = 0; et < 8; et++)
        acc1[et] = __builtin_amdgcn_mfma_f32_16x16x32_f16(sW1[(et * 2 + ks) * 64 + lane], zb8, acc1[et], 0, 0, 0);
    }
    half4 h4[8];
#pragma unroll
    for (int et = 0; et < 8; et++)
      h4[et] = half4{(f16)gelu_t(acc1[et][0]), (f16)gelu_t(acc1[et][1]),
                     (f16)gelu_t(acc1[et][2]), (f16)gelu_t(acc1[et][3])};
    // ---- FF GEMM2 (K=128 as 4x32 permuted frags; B-side weights from L2 via W2F) ----
    f32x4 acc2[4];
#pragma unroll
    for (int dt = 0; dt < 4; dt++) acc2[dt] = *(const f32x4*)(sf + 256 + dt * 16 + qh * 4);
#pragma unroll
    for (int ks = 0; ks < 4; ks++) {
      half4 a = h4[ks * 2], b = h4[ks * 2 + 1];
      half8 hb8 = half8{a[0], a[1], a[2], a[3], b[0], b[1], b[2], b[3]};
#pragma unroll
      for (int dt = 0; dt < 4; dt++)
        acc2[dt] = __builtin_amdgcn_mfma_f32_16x16x32_f16(sW2g[(dt * 4 + ks) * 64 + lane], hb8, acc2[dt], 0, 0, 0);
    }
    s = 0.f; s2 = 0.f;
#pragma unroll
    for (int dt = 0; dt < 4; dt++) {
#pragma unroll
      for (int r = 0; r < 4; r++) {
        xv[dt][r] += acc2[dt][r];
        s += xv[dt][r]; s2 += xv[dt][r] * xv[dt][r];
      }
      if constexpr (WZ) {
        half4 xo = half4{(f16)xv[dt][0], (f16)xv[dt][1], (f16)xv[dt][2], (f16)xv[dt][3]};
        *(half4*)(X + (size_t)pos * 64 + dt * 16 + qh * 4) = xo;
      }
    }
    s += __shfl_xor(s, 16); s += __shfl_xor(s, 32);
    s2 += __shfl_xor(s2, 16); s2 += __shfl_xor(s2, 32);
    float m2 = s * (1.0f / 64.0f);
    float rstd2 = rsqrtf(s2 * (1.0f / 64.0f) - m2 * m2 + 1e-5f);

    if constexpr (WZ) {
      int prow = widx * 16 + pl;
#pragma unroll
      for (int q = 0; q < 4; q++) {
        int d0 = q * 16 + qh * 4;
        f32x4 lw = *(const f32x4*)(sf + 448 + d0);
        f32x4 lb = *(const f32x4*)(sf + 512 + d0);
#pragma unroll
        for (int r = 0; r < 4; r++)
          ztile[(d0 + r) * 132 + prow] = (f16)fmaf((xv[q][r] - m2) * rstd2, lw[r], lb[r]);
      }
      __syncthreads();
      {
        int d = tid >> 3, c0 = (tid & 7) * 16;
        half8 z0 = *(const half8*)(ztile + d * 132 + c0);
        half8 z1 = *(const half8*)(ztile + d * 132 + c0 + 8);
        size_t zoff = (size_t)d * 262144 + (size_t)pt0 * 16;
        *(half8*)(Z16 + zoff + c0) = z0;
        *(half8*)(Z16 + zoff + c0 + 8) = z1;
      }
      __syncthreads();
    } else {
      // ---- fused head: z = normLN(x); u = Wf z + bfb; o = wz . relu(u) + bz ----
      const half8* sWf = (const half8*)(sm + 35072);
      const float* hf = (const float*)(sm + 43264);
      half4 hz[4];
#pragma unroll
      for (int ks = 0; ks < 4; ks++) {
        f32x4 lw = *(const f32x4*)(sf + 448 + ks * 16 + qh * 4);
        f32x4 lb = *(const f32x4*)(sf + 512 + ks * 16 + qh * 4);
        half4 z;
#pragma unroll
        for (int r = 0; r < 4; r++) z[r] = (f16)fmaf((xv[ks][r] - m2) * rstd2, lw[r], lb[r]);
        hz[ks] = z;
      }
      f32x4 acch[4];
#pragma unroll
      for (int et = 0; et < 4; et++) acch[et] = *(const f32x4*)(hf + et * 16 + qh * 4);
#pragma unroll
      for (int ks = 0; ks < 2; ks++) {
        half4 a = hz[ks * 2], b = hz[ks * 2 + 1];
        half8 zb8 = half8{a[0], a[1], a[2], a[3], b[0], b[1], b[2], b[3]};
#pragma unroll
        for (int et = 0; et < 4; et++)
          acch[et] = __builtin_amdgcn_mfma_f32_16x16x32_f16(sWf[(et * 2 + ks) * 64 + lane], zb8, acch[et], 0, 0, 0);
      }
      float o = 0.f;
#pragma unroll
      for (int et = 0; et < 4; et++) {
        f32x4 wzv = *(const f32x4*)(hf + 64 + et * 16 + qh * 4);
#pragma unroll
        for (int r = 0; r < 4; r++) {
          float rv = acch[et][r];
          rv = rv > 0.f ? rv : 0.f;
          o = fmaf(wzv[r], rv, o);
        }
      }
      o += __shfl_xor(o, 16); o += __shfl_xor(o, 32);
      if (qh == 0) outp[pos] = o + hf[128];
    }
  }
}

extern "C" void kernel_launch(void* const* d_in, const int* in_sizes, int n_in,
                              void* d_out, int out_size, void* d_ws, size_t ws_size,
                              hipStream_t stream) {
  (void)in_sizes; (void)n_in; (void)out_size; (void)ws_size;
  const float* inputs   = (const float*)d_in[0];
  const float* w_init   = (const float*)d_in[1];
  const float* b_init   = (const float*)d_in[2];
  const float* s4_ln_w  = (const float*)d_in[3];
  const float* s4_ln_b  = (const float*)d_in[4];
  const float* log_dt   = (const float*)d_in[5];
  const float* log_A    = (const float*)d_in[6];
  const float* A_imag   = (const float*)d_in[7];
  const float* C_re     = (const float*)d_in[8];
  const float* C_im     = (const float*)d_in[9];
  const float* D_skip   = (const float*)d_in[10];
  const float* s4_out_w = (const float*)d_in[11];
  const float* s4_out_b = (const float*)d_in[12];
  const float* ff_ln_w  = (const float*)d_in[13];
  const float* ff_ln_b  = (const float*)d_in[14];
  const float* ff_w1    = (const float*)d_in[15];
  const float* ff_b1    = (const float*)d_in[16];
  const float* ff_w2    = (const float*)d_in[17];
  const float* ff_b2    = (const float*)d_in[18];
  const float* norm_w   = (const float*)d_in[19];
  const float* norm_b   = (const float*)d_in[20];
  const float* w_final1 = (const float*)d_in[21];
  const float* b_final1 = (const float*)d_in[22];
  const float* w_zero   = (const float*)d_in[23];
  const float* b_zero   = (const float*)d_in[24];

  char* w8 = (char*)d_ws;
  size_t off = 0;
  f16*   X     = (f16*)(w8 + off);   off += (size_t)33554432;   // [pos][64] f16
  f16*   Z16   = (f16*)(w8 + off);   off += (size_t)33554432;   // [d][pos] f16
  f16*   Y16   = (f16*)(w8 + off);   off += (size_t)33554432;   // [pos][d] f16
  f16*   S16   = (f16*)(w8 + off);   off += (size_t)8388608;    // [d][bc][32] f16
  f16*   Sc    = (f16*)(w8 + off);   off += (size_t)8388608;    // [d][bc][32] f16
  f32x2* LCL   = (f32x2*)(w8 + off); off += 32768;
  f32x2* LC2K  = (f32x2*)(w8 + off); off += 32768;
  half8* TF    = (half8*)(w8 + off); off += (size_t)8388608;    // 4 layers x 2MB
  half8* VF    = (half8*)(w8 + off); off += (size_t)2097152;
  half8* WF    = (half8*)(w8 + off); off += (size_t)2097152;
  half8* W2F   = (half8*)(w8 + off); off += 65536;              // 4 layers x 16KB frag f16

  k_wtall<<<256, 128, 0, stream>>>(log_dt, log_A, A_imag, C_re, C_im, D_skip,
                                   LCL, LC2K, TF, VF, WF);
  k_wprep<<<4, 256, 0, stream>>>(ff_w2, W2F);
  k_init3<<<512, 512, 0, stream>>>(inputs, w_init, b_init, s4_ln_w, s4_ln_b, X, Z16);
  for (int i = 0; i < NLq; i++) {
    k_p1g<<<2048, 256, 0, stream>>>(Z16, WF + (size_t)i * 32768, S16);
    k_pass2<<<512, 256, 0, stream>>>(S16, LCL + i * 1024, LC2K + i * 1024, Sc);
    k_p3g2<<<512, 256, 0, stream>>>(Z16, Sc, TF + (size_t)i * 131072, VF + (size_t)i * 32768, Y16);
    if (i < NLq - 1) {
      k_gluff5<1><<<768, 512, 0, stream>>>(Y16, s4_out_w + i * 8192, s4_out_b + i * 128,
                                           ff_w1 + i * 8192, ff_b1 + i * 128,
                                           W2F + (size_t)i * 1024, ff_b2 + i * 64,
                                           ff_ln_w + i * 64, ff_ln_b + i * 64,
                                           s4_ln_w + (i + 1) * 64, s4_ln_b + (i + 1) * 64,
                                           X, Z16, nullptr, nullptr, nullptr, nullptr, nullptr);
    } else {
      k_gluff5<0><<<768, 512, 0, stream>>>(Y16, s4_out_w + i * 8192, s4_out_b + i * 128,
                                           ff_w1 + i * 8192, ff_b1 + i * 128,
                                           W2F + (size_t)i * 1024, ff_b2 + i * 64,
                                           ff_ln_w + i * 64, ff_ln_b + i * 64,
                                           norm_w, norm_b,
                                           X, Z16, w_final1, b_final1, w_zero, b_zero,
                                           (float*)d_out);
    }
  }
}

// Round 14
// 509.251 us; speedup vs baseline: 1.0576x; 1.0005x over previous
//
#include <hip/hip_runtime.h>
#include <cmath>

constexpr int Bq = 8, Lq = 32768, Dq = 64, Nq = 16, NLq = 4;
constexpr int CLq = 128, NCq = 256;           // NCq*CLq == Lq ; chunks per batch
constexpr int PT = Bq * Lq / 16;              // 16384 position-tiles of 16

typedef _Float16 f16;
typedef _Float16 half2t __attribute__((ext_vector_type(2)));
typedef _Float16 half4 __attribute__((ext_vector_type(4)));
typedef _Float16 half8 __attribute__((ext_vector_type(8)));
typedef float f32x4 __attribute__((ext_vector_type(4)));
typedef float f32x2 __attribute__((ext_vector_type(2)));

static __device__ __forceinline__ float sigm(float x) { return 1.0f / (1.0f + __expf(-x)); }
static __device__ __forceinline__ float gelu_t(float x) {
  return x * sigm(1.5957691216057308f * fmaf(0.044715f * x * x, x, x));
}

// -------- k_wtall: setup + all layers' frag-ordered f16 matrices TF/VF/WF; LCL, LC2K --------
__global__ __launch_bounds__(128) void k_wtall(
    const float* __restrict__ log_dt, const float* __restrict__ log_A_real,
    const float* __restrict__ A_imag, const float* __restrict__ C_re,
    const float* __restrict__ C_im, const float* __restrict__ dskip,
    f32x2* __restrict__ LCL, f32x2* __restrict__ LC2K, half8* __restrict__ TF,
    half8* __restrict__ VF, half8* __restrict__ WF) {
  __shared__ f32x2 pw[129][16];
  __shared__ f32x2 lamS[16], dcS[16];
  __shared__ float Ks[128];
  int d = blockIdx.x & 63, L = blockIdx.x >> 6;
  half8* TFl = TF + (size_t)L * 131072;
  half8* VFl = VF + (size_t)L * 32768;
  half8* WFl = WF + (size_t)L * 32768;
  int t = threadIdx.x;
  if (t < 16) {
    int di = L * 64 + d;
    int idx = di * 16 + t;
    float dt = expf(log_dt[di]);
    float Ar = -expf(log_A_real[idx]);
    float Ai = A_imag[idx];
    float dr = Ar * dt, dmi = Ai * dt;
    float er = expf(dr);
    float lr = er * cosf(dmi), li = er * sinf(dmi);
    float inv = 1.0f / (Ar * Ar + Ai * Ai);
    float e1r = lr - 1.0f, e1i = li;
    float qr = (e1r * Ar + e1i * Ai) * inv;
    float qi = (e1i * Ar - e1r * Ai) * inv;
    float cr = C_re[idx], ci = C_im[idx];
    lamS[t] = f32x2{lr, li};
    dcS[t] = f32x2{2.0f * (cr * qr - ci * qi), 2.0f * (cr * qi + ci * qr)};
    float erc = expf(dr * 128.0f);
    f32x2 l128 = f32x2{erc * cosf(dmi * 128.0f), erc * sinf(dmi * 128.0f)};
    pw[128][t] = l128;
    LCL[(size_t)L * 1024 + d * 16 + t] = l128;
    float br = l128.x, bi = l128.y;
#pragma unroll
    for (int q = 0; q < 4; q++) {
      float t2 = br * br - bi * bi;
      bi = 2.f * br * bi; br = t2;
    }
    LC2K[(size_t)L * 1024 + d * 16 + t] = f32x2{br, bi};
  }
  __syncthreads();
#pragma unroll
  for (int n = 0; n < 16; n++) {
    f32x2 lam = lamS[n];
    float pr = 1.f, pi = 0.f, br = lam.x, bi = lam.y;
    int e = t;
    while (e) {
      if (e & 1) { float tt = pr * br - pi * bi; pi = fmaf(pr, bi, pi * br); pr = tt; }
      float t2 = br * br - bi * bi; bi = 2.f * br * bi; br = t2; e >>= 1;
    }
    pw[t][n] = f32x2{pr, pi};
  }
  __syncthreads();
  {
    float k = 0.f;
#pragma unroll
    for (int n = 0; n < 16; n++) {
      f32x2 dc = dcS[n];
      f32x2 p = pw[t][n];
      k += dc.x * p.x - dc.y * p.y;
    }
    if (t == 0) k += dskip[L * 64 + d];
    Ks[t] = k;
  }
  __syncthreads();
  for (int s = t; s < 2048; s += 128) {
    int ln = s & 63, kt = (s >> 6) & 3, mt = s >> 8;
    int jo = mt * 16 + (ln & 15);
    int ji0 = kt * 32 + (ln >> 4) * 8;
    half8 v;
#pragma unroll
    for (int jj = 0; jj < 8; jj++) {
      int ji = ji0 + jj;
      v[jj] = (jo >= ji) ? (f16)Ks[jo - ji] : (f16)0.f;
    }
    TFl[(size_t)d * 2048 + s] = v;
  }
  for (int s = t; s < 512; s += 128) {
    int ln = s & 63, mt = s >> 6;
    int jo = mt * 16 + (ln & 15);
    int q0 = (ln >> 4) * 8;
    half8 v;
#pragma unroll
    for (int jj = 0; jj < 8; jj++) {
      int q = q0 + jj, n = q >> 1;
      f32x2 dc = dcS[n];
      f32x2 p = pw[jo + 1][n];
      float wr = dc.x * p.x - dc.y * p.y;
      float wi = dc.x * p.y + dc.y * p.x;
      v[jj] = (q & 1) ? (f16)(-wi) : (f16)wr;
    }
    VFl[(size_t)d * 512 + s] = v;
  }
  for (int s = t; s < 512; s += 128) {
    int ln = s & 63, kt = (s >> 6) & 3, nt = s >> 8;
    int p_ = nt * 16 + (ln & 15);
    int n = p_ >> 1;
    int j0 = kt * 32 + (ln >> 4) * 8;
    half8 v;
#pragma unroll
    for (int jj = 0; jj < 8; jj++) {
      f32x2 p = pw[127 - (j0 + jj)][n];
      v[jj] = (p_ & 1) ? (f16)p.y : (f16)p.x;
    }
    WFl[(size_t)d * 512 + s] = v;
  }
}

// -------- k_wprep: frag-order ff_w2 (PERMUTED k) into f16 W2F[4][1024] --------
__global__ __launch_bounds__(256) void k_wprep(
    const float* __restrict__ W2all, half8* __restrict__ W2F) {
  int L = blockIdx.x;
  const float* W2 = W2all + L * 8192;
  half8* out = W2F + (size_t)L * 1024;
  int tid = threadIdx.x;
#pragma unroll
  for (int it = 0; it < 4; it++) {
    int s = it * 256 + tid;
    int l = s & 63, ks = (s >> 6) & 3, dt = s >> 8;
    int pls = l & 15, qhs = l >> 4;
    const float* wp = W2 + (dt * 16 + pls) * 128 + ks * 32 + qhs * 4;
    f32x4 w0 = *(const f32x4*)wp;
    f32x4 w1 = *(const f32x4*)(wp + 16);
    out[s] = half8{(f16)w0[0], (f16)w0[1], (f16)w0[2], (f16)w0[3],
                   (f16)w1[0], (f16)w1[1], (f16)w1[2], (f16)w1[3]};
  }
}

// -------- k_init3: x = relu(w_init*in + b_init) -> X f16; z = s4LN0(x) -> Z16 --------
__global__ __launch_bounds__(512) void k_init3(
    const float* __restrict__ inp, const float* __restrict__ w_init,
    const float* __restrict__ b_init, const float* __restrict__ lnw,
    const float* __restrict__ lnb, f16* __restrict__ X, f16* __restrict__ Z16) {
  __shared__ __align__(16) f16 ztile[64 * 132];
  int tid = threadIdx.x;
  int widx = tid >> 6, lane = tid & 63;
  int pl = lane & 15, qh = lane >> 4;
  for (int k = 0; k < 4; ++k) {
    int pt = blockIdx.x * 8 + widx + k * 4096;
    int pos = pt * 16 + pl;
    float v = inp[pos];
    float s = 0.f, s2 = 0.f;
    f32x4 o[4];
#pragma unroll
    for (int q = 0; q < 4; q++) {
      int d0 = q * 16 + qh * 4;
      f32x4 w4 = *(const f32x4*)(w_init + d0);
      f32x4 b4 = *(const f32x4*)(b_init + d0);
#pragma unroll
      for (int j = 0; j < 4; j++) {
        float t = fmaf(w4[j], v, b4[j]);
        t = t > 0.f ? t : 0.f;
        o[q][j] = t; s += t; s2 += t * t;
      }
      half4 xo = half4{(f16)o[q][0], (f16)o[q][1], (f16)o[q][2], (f16)o[q][3]};
      *(half4*)(X + (size_t)pos * 64 + d0) = xo;
    }
    s += __shfl_xor(s, 16); s += __shfl_xor(s, 32);
    s2 += __shfl_xor(s2, 16); s2 += __shfl_xor(s2, 32);
    float m = s * (1.0f / 64.0f);
    float rstd = rsqrtf(s2 * (1.0f / 64.0f) - m * m + 1e-5f);
    int prow = widx * 16 + pl;
#pragma unroll
    for (int q = 0; q < 4; q++) {
      int d0 = q * 16 + qh * 4;
      f32x4 lw = *(const f32x4*)(lnw + d0);
      f32x4 lb = *(const f32x4*)(lnb + d0);
#pragma unroll
      for (int r = 0; r < 4; r++)
        ztile[(d0 + r) * 132 + prow] = (f16)fmaf((o[q][r] - m) * rstd, lw[r], lb[r]);
    }
    __syncthreads();
    {
      int d = tid >> 3, c0 = (tid & 7) * 16;
      half8 z0 = *(const half8*)(ztile + d * 132 + c0);
      half8 z1 = *(const half8*)(ztile + d * 132 + c0 + 8);
      size_t zoff = (size_t)d * 262144 + (size_t)(blockIdx.x * 8 + k * 4096) * 16;
      *(half8*)(Z16 + zoff + c0) = z0;
      *(half8*)(Z16 + zoff + c0 + 8) = z1;
    }
    __syncthreads();
  }
}

// -------- k_p1g: chunk end-states S16[d][bc][p32] = Z(m=bc,k=j) @ Wend(k=j,n=p) --------
__global__ __launch_bounds__(256) void k_p1g(
    const f16* __restrict__ Z16, const half8* __restrict__ WF, f16* __restrict__ S16) {
  int tid = threadIdx.x;
  int lane = tid & 63;
  int task = blockIdx.x * 4 + (tid >> 6);
  int d = task >> 7, bct = task & 127;
  int bc0 = bct * 16;
  int pl = lane & 15, qh = lane >> 4;
  half8 az[4];
  const f16* zp = Z16 + ((size_t)d * 2048 + bc0 + pl) * 128 + qh * 8;
#pragma unroll
  for (int kt = 0; kt < 4; kt++) az[kt] = *(const half8*)(zp + kt * 32);
#pragma unroll
  for (int nt = 0; nt < 2; nt++) {
    f32x4 acc = f32x4{0.f, 0.f, 0.f, 0.f};
#pragma unroll
    for (int kt = 0; kt < 4; kt++)
      acc = __builtin_amdgcn_mfma_f32_16x16x32_f16(az[kt], WF[(size_t)d * 512 + (nt * 4 + kt) * 64 + lane], acc, 0, 0, 0);
#pragma unroll
    for (int r = 0; r < 4; r++)
      S16[((size_t)d * 2048 + bc0 + qh * 4 + r) * 32 + nt * 16 + pl] = (f16)acc[r];
  }
}

// -------- k_pass2: 3-phase block-local scan. grid 512 = (d,b); 256 thr = (g16, n16) --------
__global__ __launch_bounds__(256) void k_pass2(
    const f16* __restrict__ S16, const f32x2* __restrict__ LCLl,
    const f32x2* __restrict__ LC2Kl, f16* __restrict__ Sc) {
  __shared__ f32x2 gc[16][17];
  int blk = blockIdx.x;               // d*8 + b
  int d = blk >> 3, b = blk & 7;
  int t = threadIdx.x;                // g*16 + n
  int n = t & 15, g = t >> 4;
  f32x2 lam = LCLl[d * 16 + n];
  size_t base = ((size_t)d * 2048 + b * 256 + g * 16) * 32 + 2 * n;
  const f16* sp = S16 + base;
  float cr = 0.f, ci = 0.f;
#pragma unroll 4
  for (int j = 0; j < 16; j++) {
    half2t v = *(const half2t*)(sp + (size_t)j * 32);
    float nr = fmaf(lam.x, cr, fmaf(-lam.y, ci, (float)v[0]));
    float ni = fmaf(lam.x, ci, fmaf(lam.y, cr, (float)v[1]));
    cr = nr; ci = ni;
  }
  gc[g][n] = f32x2{cr, ci};
  __syncthreads();
  f32x2 l2 = LC2Kl[d * 16 + n];
  float er = 0.f, ei = 0.f;
  for (int gg = 0; gg < g; gg++) {
    f32x2 c = gc[gg][n];
    float nr = fmaf(l2.x, er, fmaf(-l2.y, ei, c.x));
    float ni = fmaf(l2.x, ei, fmaf(l2.y, er, c.y));
    er = nr; ei = ni;
  }
  f16* cp = Sc + base;
  float cr2 = er, ci2 = ei;
#pragma unroll 4
  for (int j = 0; j < 16; j++) {
    *(half2t*)(cp + (size_t)j * 32) = half2t{(f16)cr2, (f16)ci2};
    half2t v = *(const half2t*)(sp + (size_t)j * 32);
    float nr = fmaf(lam.x, cr2, fmaf(-lam.y, ci2, (float)v[0]));
    float ni = fmaf(lam.x, ci2, fmaf(lam.y, cr2, (float)v[1]));
    cr2 = nr; ci2 = ni;
  }
}

// -------- k_p3g2: y = T@z + V@carry, gelu -> Y16[pos][d] (d-packed half4), grid 512 --------
__global__ __launch_bounds__(256) void k_p3g2(
    const f16* __restrict__ Z16, const f16* __restrict__ Sc,
    const half8* __restrict__ TF, const half8* __restrict__ VF,
    f16* __restrict__ Y16) {
  int tid = threadIdx.x;
  int lane = tid & 63, widx = tid >> 6;
  int bct = blockIdx.x & 127, dg = blockIdx.x >> 7;  // grid 512: 4 dg x 128 bct
  int bc0 = bct * 16;
  int dbase = dg * 16 + widx * 4;
  int pl = lane & 15, qh = lane >> 4;
  half8 zb[4][4];
  half8 sb[4];
#pragma unroll
  for (int di = 0; di < 4; di++) {
    int d = dbase + di;
    const f16* zp = Z16 + ((size_t)d * 2048 + bc0 + pl) * 128 + qh * 8;
#pragma unroll
    for (int kt = 0; kt < 4; kt++) zb[di][kt] = *(const half8*)(zp + kt * 32);
    sb[di] = *(const half8*)(Sc + ((size_t)d * 2048 + bc0 + pl) * 32 + qh * 8);
  }
#pragma unroll
  for (int mt = 0; mt < 8; mt++) {
    const int KTM = mt / 2 + 1;  // causal: tiles with ji0 <= jo_max
    f32x4 acc[4];
#pragma unroll
    for (int di = 0; di < 4; di++) {
      int d = dbase + di;
      acc[di] = f32x4{0.f, 0.f, 0.f, 0.f};
      const half8* tfp = TF + ((size_t)d * 8 + mt) * 256 + lane;
#pragma unroll
      for (int kt = 0; kt < KTM; kt++)
        acc[di] = __builtin_amdgcn_mfma_f32_16x16x32_f16(tfp[kt * 64], zb[di][kt], acc[di], 0, 0, 0);
      acc[di] = __builtin_amdgcn_mfma_f32_16x16x32_f16(VF[((size_t)d * 8 + mt) * 64 + lane], sb[di], acc[di], 0, 0, 0);
    }
#pragma unroll
    for (int r = 0; r < 4; r++) {
      int pos = (bc0 + pl) * 128 + mt * 16 + qh * 4 + r;
      half4 pk = half4{(f16)gelu_t(acc[0][r]), (f16)gelu_t(acc[1][r]),
                       (f16)gelu_t(acc[2][r]), (f16)gelu_t(acc[3][r])};
      *(half4*)(Y16 + (size_t)pos * 64 + dbase) = pk;
    }
  }
}

// ======== Fused GLU+FF(+next-layer z | +head); W2 frags from global (L2) ========
// LDS 51968 B -> 3 blocks/CU at 512 thr IF VGPR <= 64 (8-wave register boundary).
// NO min-waves hint: the allocator must pick VGPR freely (R12/R13: hints force spill).
template <int WZ>
__global__ __launch_bounds__(512) void k_gluff5(
    const f16* __restrict__ Y16, const float* __restrict__ Wg, const float* __restrict__ bg,
    const float* __restrict__ W1, const float* __restrict__ b1,
    const half8* __restrict__ W2F, const float* __restrict__ b2,
    const float* __restrict__ lnw, const float* __restrict__ lnb,
    const float* __restrict__ nlnw, const float* __restrict__ nlnb,
    f16* __restrict__ X, f16* __restrict__ Z16,
    const float* __restrict__ Wf, const float* __restrict__ bfb,
    const float* __restrict__ wz, const float* __restrict__ bz,
    float* __restrict__ outp) {
  __shared__ __align__(16) char smem[51968];
  int tid = threadIdx.x;
#pragma unroll
  for (int it = 0; it < 2; it++) {           // sWg: NATURAL k
    int s = it * 512 + tid;
    int l = s & 63, ks = (s >> 6) & 1, et = s >> 7;
    const float* wp = Wg + (et * 16 + (l & 15)) * 64 + ks * 32 + (l >> 4) * 8;
    f32x4 w0 = *(const f32x4*)wp, w1 = *(const f32x4*)(wp + 4);
    *(half8*)(smem + s * 16) = half8{(f16)w0[0], (f16)w0[1], (f16)w0[2], (f16)w0[3],
                                     (f16)w1[0], (f16)w1[1], (f16)w1[2], (f16)w1[3]};
  }
#pragma unroll
  for (int it = 0; it < 2; it++) {           // sW1: PERMUTED k
    int s = it * 512 + tid;
    int l = s & 63, ks = (s >> 6) & 1, et = s >> 7;
    int pls = l & 15, qhs = l >> 4;
    const float* wp = W1 + (et * 16 + pls) * 64 + ks * 32 + qhs * 4;
    f32x4 w0 = *(const f32x4*)wp;
    f32x4 w1 = *(const f32x4*)(wp + 16);
    *(half8*)(smem + 16384 + s * 16) = half8{(f16)w0[0], (f16)w0[1], (f16)w0[2], (f16)w0[3],
                                             (f16)w1[0], (f16)w1[1], (f16)w1[2], (f16)w1[3]};
  }
  for (int idx = tid; idx < 576; idx += 512) {
    float v;
    if (idx < 128) v = bg[idx];
    else if (idx < 256) v = b1[idx - 128];
    else if (idx < 320) v = b2[idx - 256];
    else if (idx < 384) v = lnw[idx - 320];
    else if (idx < 448) v = lnb[idx - 384];
    else if (idx < 512) v = nlnw[idx - 448];
    else v = nlnb[idx - 512];
    ((float*)(smem + 32768))[idx] = v;
  }
  if constexpr (!WZ) {
    if (tid < 512) {                         // sWf: PERMUTED k (head GEMM)
      int s = tid;
      int l = s & 63, ks = (s >> 6) & 1, et = s >> 7;  // et < 4
      int pls = l & 15, qhs = l >> 4;
      const float* wp = Wf + (et * 16 + pls) * 64 + ks * 32 + qhs * 4;
      f32x4 w0 = *(const f32x4*)wp;
      f32x4 w1 = *(const f32x4*)(wp + 16);
      *(half8*)(smem + 35072 + s * 16) = half8{(f16)w0[0], (f16)w0[1], (f16)w0[2], (f16)w0[3],
                                               (f16)w1[0], (f16)w1[1], (f16)w1[2], (f16)w1[3]};
    }
    if (tid < 129) {
      float v = tid < 64 ? bfb[tid] : (tid < 128 ? wz[tid - 64] : bz[0]);
      ((float*)(smem + 43264))[tid] = v;
    }
  }
  __syncthreads();
  int lane = tid & 63, pl = lane & 15, qh = lane >> 4;
  int widx = tid >> 6;
  f16* ztile = (f16*)(smem + 35072);

  for (int pt0 = blockIdx.x * 8; pt0 < PT; pt0 += 6144) {   // grid 768, block-uniform rounds
    int pt = pt0 + widx;
    int pos = pt * 16 + pl;
    half8 yb0 = *(const half8*)(Y16 + (size_t)pos * 64 + qh * 8);
    half8 yb1 = *(const half8*)(Y16 + (size_t)pos * 64 + 32 + qh * 8);
    f32x4 xv[4];
#pragma unroll
    for (int q = 0; q < 4; q++) {
      half4 xh = *(const half4*)(X + (size_t)pos * 64 + q * 16 + qh * 4);
#pragma unroll
      for (int r = 0; r < 4; r++) xv[q][r] = (float)xh[r];
    }

    unsigned sb = 0, o2 = 0;
    asm volatile("" : "+v"(sb));                // opaque: defeats LICM on LDS (anti-spill)
    asm volatile("" : "+v"(o2));                // opaque: defeats LICM on W2F global frags
    const char* sm = smem + sb;
    const half8* sWg = (const half8*)sm;
    const half8* sW1 = (const half8*)(sm + 16384);
    const half8* sW2g = W2F + o2;
    const float* sf = (const float*)(sm + 32768);
    // ---- GLU ----
    f32x4 accg[8];
#pragma unroll
    for (int et = 0; et < 8; et++) accg[et] = *(const f32x4*)(sf + et * 16 + qh * 4);
#pragma unroll
    for (int et = 0; et < 8; et++)
      accg[et] = __builtin_amdgcn_mfma_f32_16x16x32_f16(sWg[(et * 2) * 64 + lane], yb0, accg[et], 0, 0, 0);
#pragma unroll
    for (int et = 0; et < 8; et++)
      accg[et] = __builtin_amdgcn_mfma_f32_16x16x32_f16(sWg[(et * 2 + 1) * 64 + lane], yb1, accg[et], 0, 0, 0);
    float s = 0.f, s2 = 0.f;
#pragma unroll
    for (int q = 0; q < 4; q++)
#pragma unroll
      for (int r = 0; r < 4; r++) {
        xv[q][r] += accg[q][r] * sigm(accg[q + 4][r]);
        s += xv[q][r]; s2 += xv[q][r] * xv[q][r];
      }
    s += __shfl_xor(s, 16); s += __shfl_xor(s, 32);
    s2 += __shfl_xor(s2, 16); s2 += __shfl_xor(s2, 32);
    float m = s * (1.0f / 64.0f);
    float rstd = rsqrtf(s2 * (1.0f / 64.0f) - m * m + 1e-5f);
    // ---- FF GEMM1 (K=32 permuted frags) ----
    half4 zb4[4];
#pragma unroll
    for (int ks = 0; ks < 4; ks++) {
      f32x4 lw = *(const f32x4*)(sf + 320 + ks * 16 + qh * 4);
      f32x4 lb = *(const f32x4*)(sf + 384 + ks * 16 + qh * 4);
      half4 z;
#pragma unroll
      for (int r = 0; r < 4; r++) z[r] = (f16)fmaf((xv[ks][r] - m) * rstd, lw[r], lb[r]);
      zb4[ks] = z;
    }
    f32x4 acc1[8];
#pragma unroll
    for (int et = 0; et < 8; et++) acc1[et] = *(const f32x4*)(sf + 128 + et * 16 + qh * 4);
#pragma unroll
    for (int ks = 0; ks < 2; ks++) {
      half4 a = zb4[ks * 2], b = zb4[ks * 2 + 1];
      half8 zb8 = half8{a[0], a[1], a[2], a[3], b[0], b[1], b[2], b[3]};
#pragma unroll
      for (int et = 0; et < 8; et++)
        acc1[et] = __builtin_amdgcn_mfma_f32_16x16x32_f16(sW1[(et * 2 + ks) * 64 + lane], zb8, acc1[et], 0, 0, 0);
    }
    half4 h4[8];
#pragma unroll
    for (int et = 0; et < 8; et++)
      h4[et] = half4{(f16)gelu_t(acc1[et][0]), (f16)gelu_t(acc1[et][1]),
                     (f16)gelu_t(acc1[et][2]), (f16)gelu_t(acc1[et][3])};
    // ---- FF GEMM2 (K=128 as 4x32 permuted frags; B-side weights from L2 via W2F) ----
    f32x4 acc2[4];
#pragma unroll
    for (int dt = 0; dt < 4; dt++) acc2[dt] = *(const f32x4*)(sf + 256 + dt * 16 + qh * 4);
#pragma unroll
    for (int ks = 0; ks < 4; ks++) {
      half4 a = h4[ks * 2], b = h4[ks * 2 + 1];
      half8 hb8 = half8{a[0], a[1], a[2], a[3], b[0], b[1], b[2], b[3]};
#pragma unroll
      for (int dt = 0; dt < 4; dt++)
        acc2[dt] = __builtin_amdgcn_mfma_f32_16x16x32_f16(sW2g[(dt * 4 + ks) * 64 + lane], hb8, acc2[dt], 0, 0, 0);
    }
    s = 0.f; s2 = 0.f;
#pragma unroll
    for (int dt = 0; dt < 4; dt++) {
#pragma unroll
      for (int r = 0; r < 4; r++) {
        xv[dt][r] += acc2[dt][r];
        s += xv[dt][r]; s2 += xv[dt][r] * xv[dt][r];
      }
      if constexpr (WZ) {
        half4 xo = half4{(f16)xv[dt][0], (f16)xv[dt][1], (f16)xv[dt][2], (f16)xv[dt][3]};
        *(half4*)(X + (size_t)pos * 64 + dt * 16 + qh * 4) = xo;
      }
    }
    s += __shfl_xor(s, 16); s += __shfl_xor(s, 32);
    s2 += __shfl_xor(s2, 16); s2 += __shfl_xor(s2, 32);
    float m2 = s * (1.0f / 64.0f);
    float rstd2 = rsqrtf(s2 * (1.0f / 64.0f) - m2 * m2 + 1e-5f);

    if constexpr (WZ) {
      int prow = widx * 16 + pl;
#pragma unroll
      for (int q = 0; q < 4; q++) {
        int d0 = q * 16 + qh * 4;
        f32x4 lw = *(const f32x4*)(sf + 448 + d0);
        f32x4 lb = *(const f32x4*)(sf + 512 + d0);
#pragma unroll
        for (int r = 0; r < 4; r++)
          ztile[(d0 + r) * 132 + prow] = (f16)fmaf((xv[q][r] - m2) * rstd2, lw[r], lb[r]);
      }
      __syncthreads();
      {
        int d = tid >> 3, c0 = (tid & 7) * 16;
        half8 z0 = *(const half8*)(ztile + d * 132 + c0);
        half8 z1 = *(const half8*)(ztile + d * 132 + c0 + 8);
        size_t zoff = (size_t)d * 262144 + (size_t)pt0 * 16;
        *(half8*)(Z16 + zoff + c0) = z0;
        *(half8*)(Z16 + zoff + c0 + 8) = z1;
      }
      __syncthreads();
    } else {
      // ---- fused head: z = normLN(x); u = Wf z + bfb; o = wz . relu(u) + bz ----
      const half8* sWf = (const half8*)(sm + 35072);
      const float* hf = (const float*)(sm + 43264);
      half4 hz[4];
#pragma unroll
      for (int ks = 0; ks < 4; ks++) {
        f32x4 lw = *(const f32x4*)(sf + 448 + ks * 16 + qh * 4);
        f32x4 lb = *(const f32x4*)(sf + 512 + ks * 16 + qh * 4);
        half4 z;
#pragma unroll
        for (int r = 0; r < 4; r++) z[r] = (f16)fmaf((xv[ks][r] - m2) * rstd2, lw[r], lb[r]);
        hz[ks] = z;
      }
      f32x4 acch[4];
#pragma unroll
      for (int et = 0; et < 4; et++) acch[et] = *(const f32x4*)(hf + et * 16 + qh * 4);
#pragma unroll
      for (int ks = 0; ks < 2; ks++) {
        half4 a = hz[ks * 2], b = hz[ks * 2 + 1];
        half8 zb8 = half8{a[0], a[1], a[2], a[3], b[0], b[1], b[2], b[3]};
#pragma unroll
        for (int et = 0; et < 4; et++)
          acch[et] = __builtin_amdgcn_mfma_f32_16x16x32_f16(sWf[(et * 2 + ks) * 64 + lane], zb8, acch[et], 0, 0, 0);
      }
      float o = 0.f;
#pragma unroll
      for (int et = 0; et < 4; et++) {
        f32x4 wzv = *(const f32x4*)(hf + 64 + et * 16 + qh * 4);
#pragma unroll
        for (int r = 0; r < 4; r++) {
          float rv = acch[et][r];
          rv = rv > 0.f ? rv : 0.f;
          o = fmaf(wzv[r], rv, o);
        }
      }
      o += __shfl_xor(o, 16); o += __shfl_xor(o, 32);
      if (qh == 0) outp[pos] = o + hf[128];
    }
  }
}

extern "C" void kernel_launch(void* const* d_in, const int* in_sizes, int n_in,
                              void* d_out, int out_size, void* d_ws, size_t ws_size,
                              hipStream_t stream) {
  (void)in_sizes; (void)n_in; (void)out_size; (void)ws_size;
  const float* inputs   = (const float*)d_in[0];
  const float* w_init   = (const float*)d_in[1];
  const float* b_init   = (const float*)d_in[2];
  const float* s4_ln_w  = (const float*)d_in[3];
  const float* s4_ln_b  = (const float*)d_in[4];
  const float* log_dt   = (const float*)d_in[5];
  const float* log_A    = (const float*)d_in[6];
  const float* A_imag   = (const float*)d_in[7];
  const float* C_re     = (const float*)d_in[8];
  const float* C_im     = (const float*)d_in[9];
  const float* D_skip   = (const float*)d_in[10];
  const float* s4_out_w = (const float*)d_in[11];
  const float* s4_out_b = (const float*)d_in[12];
  const float* ff_ln_w  = (const float*)d_in[13];
  const float* ff_ln_b  = (const float*)d_in[14];
  const float* ff_w1    = (const float*)d_in[15];
  const float* ff_b1    = (const float*)d_in[16];
  const float* ff_w2    = (const float*)d_in[17];
  const float* ff_b2    = (const float*)d_in[18];
  const float* norm_w   = (const float*)d_in[19];
  const float* norm_b   = (const float*)d_in[20];
  const float* w_final1 = (const float*)d_in[21];
  const float* b_final1 = (const float*)d_in[22];
  const float* w_zero   = (const float*)d_in[23];
  const float* b_zero   = (const float*)d_in[24];

  char* w8 = (char*)d_ws;
  size_t off = 0;
  f16*   X     = (f16*)(w8 + off);   off += (size_t)33554432;   // [pos][64] f16
  f16*   Z16   = (f16*)(w8 + off);   off += (size_t)33554432;   // [d][pos] f16
  f16*   Y16   = (f16*)(w8 + off);   off += (size_t)33554432;   // [pos][d] f16
  f16*   S16   = (f16*)(w8 + off);   off += (size_t)8388608;    // [d][bc][32] f16
  f16*   Sc    = (f16*)(w8 + off);   off += (size_t)8388608;    // [d][bc][32] f16
  f32x2* LCL   = (f32x2*)(w8 + off); off += 32768;
  f32x2* LC2K  = (f32x2*)(w8 + off); off += 32768;
  half8* TF    = (half8*)(w8 + off); off += (size_t)8388608;    // 4 layers x 2MB
  half8* VF    = (half8*)(w8 + off); off += (size_t)2097152;
  half8* WF    = (half8*)(w8 + off); off += (size_t)2097152;
  half8* W2F   = (half8*)(w8 + off); off += 65536;              // 4 layers x 16KB frag f16

  k_wtall<<<256, 128, 0, stream>>>(log_dt, log_A, A_imag, C_re, C_im, D_skip,
                                   LCL, LC2K, TF, VF, WF);
  k_wprep<<<4, 256, 0, stream>>>(ff_w2, W2F);
  k_init3<<<512, 512, 0, stream>>>(inputs, w_init, b_init, s4_ln_w, s4_ln_b, X, Z16);
  for (int i = 0; i < NLq; i++) {
    k_p1g<<<2048, 256, 0, stream>>>(Z16, WF + (size_t)i * 32768, S16);
    k_pass2<<<512, 256, 0, stream>>>(S16, LCL + i * 1024, LC2K + i * 1024, Sc);
    k_p3g2<<<512, 256, 0, stream>>>(Z16, Sc, TF + (size_t)i * 131072, VF + (size_t)i * 32768, Y16);
    if (i < NLq - 1) {
      k_gluff5<1><<<768, 512, 0, stream>>>(Y16, s4_out_w + i * 8192, s4_out_b + i * 128,
                                           ff_w1 + i * 8192, ff_b1 + i * 128,
                                           W2F + (size_t)i * 1024, ff_b2 + i * 64,
                                           ff_ln_w + i * 64, ff_ln_b + i * 64,
                                           s4_ln_w + (i + 1) * 64, s4_ln_b + (i + 1) * 64,
                                           X, Z16, nullptr, nullptr, nullptr, nullptr, nullptr);
    } else {
      k_gluff5<0><<<768, 512, 0, stream>>>(Y16, s4_out_w + i * 8192, s4_out_b + i * 128,
                                           ff_w1 + i * 8192, ff_b1 + i * 128,
                                           W2F + (size_t)i * 1024, ff_b2 + i * 64,
                                           ff_ln_w + i * 64, ff_ln_b + i * 64,
                                           norm_w, norm_b,
                                           X, Z16, w_final1, b_final1, w_zero, b_zero,
                                           (float*)d_out);
    }
  }
}

// Round 15
// 457.053 us; speedup vs baseline: 1.1784x; 1.1142x over previous
//
#include <hip/hip_runtime.h>
#include <cmath>

constexpr int Bq = 8, Lq = 32768, Dq = 64, Nq = 16, NLq = 4;
constexpr int CLq = 128, NCq = 256;           // NCq*CLq == Lq ; chunks per batch
constexpr int PT = Bq * Lq / 16;              // 16384 position-tiles of 16

typedef _Float16 f16;
typedef _Float16 half2t __attribute__((ext_vector_type(2)));
typedef _Float16 half4 __attribute__((ext_vector_type(4)));
typedef _Float16 half8 __attribute__((ext_vector_type(8)));
typedef float f32x4 __attribute__((ext_vector_type(4)));
typedef float f32x2 __attribute__((ext_vector_type(2)));

static __device__ __forceinline__ float sigm(float x) { return 1.0f / (1.0f + __expf(-x)); }
static __device__ __forceinline__ float gelu_t(float x) {
  return x * sigm(1.5957691216057308f * fmaf(0.044715f * x * x, x, x));
}

// -------- k_wtall: setup + all layers' frag-ordered f16 matrices TF/VF/WF; LCL, LC2K --------
__global__ __launch_bounds__(128) void k_wtall(
    const float* __restrict__ log_dt, const float* __restrict__ log_A_real,
    const float* __restrict__ A_imag, const float* __restrict__ C_re,
    const float* __restrict__ C_im, const float* __restrict__ dskip,
    f32x2* __restrict__ LCL, f32x2* __restrict__ LC2K, half8* __restrict__ TF,
    half8* __restrict__ VF, half8* __restrict__ WF) {
  __shared__ f32x2 pw[129][16];
  __shared__ f32x2 lamS[16], dcS[16];
  __shared__ float Ks[128];
  int d = blockIdx.x & 63, L = blockIdx.x >> 6;
  half8* TFl = TF + (size_t)L * 131072;
  half8* VFl = VF + (size_t)L * 32768;
  half8* WFl = WF + (size_t)L * 32768;
  int t = threadIdx.x;
  if (t < 16) {
    int di = L * 64 + d;
    int idx = di * 16 + t;
    float dt = expf(log_dt[di]);
    float Ar = -expf(log_A_real[idx]);
    float Ai = A_imag[idx];
    float dr = Ar * dt, dmi = Ai * dt;
    float er = expf(dr);
    float lr = er * cosf(dmi), li = er * sinf(dmi);
    float inv = 1.0f / (Ar * Ar + Ai * Ai);
    float e1r = lr - 1.0f, e1i = li;
    float qr = (e1r * Ar + e1i * Ai) * inv;
    float qi = (e1i * Ar - e1r * Ai) * inv;
    float cr = C_re[idx], ci = C_im[idx];
    lamS[t] = f32x2{lr, li};
    dcS[t] = f32x2{2.0f * (cr * qr - ci * qi), 2.0f * (cr * qi + ci * qr)};
    float erc = expf(dr * 128.0f);
    f32x2 l128 = f32x2{erc * cosf(dmi * 128.0f), erc * sinf(dmi * 128.0f)};
    pw[128][t] = l128;
    LCL[(size_t)L * 1024 + d * 16 + t] = l128;
    float br = l128.x, bi = l128.y;
#pragma unroll
    for (int q = 0; q < 4; q++) {
      float t2 = br * br - bi * bi;
      bi = 2.f * br * bi; br = t2;
    }
    LC2K[(size_t)L * 1024 + d * 16 + t] = f32x2{br, bi};
  }
  __syncthreads();
#pragma unroll
  for (int n = 0; n < 16; n++) {
    f32x2 lam = lamS[n];
    float pr = 1.f, pi = 0.f, br = lam.x, bi = lam.y;
    int e = t;
    while (e) {
      if (e & 1) { float tt = pr * br - pi * bi; pi = fmaf(pr, bi, pi * br); pr = tt; }
      float t2 = br * br - bi * bi; bi = 2.f * br * bi; br = t2; e >>= 1;
    }
    pw[t][n] = f32x2{pr, pi};
  }
  __syncthreads();
  {
    float k = 0.f;
#pragma unroll
    for (int n = 0; n < 16; n++) {
      f32x2 dc = dcS[n];
      f32x2 p = pw[t][n];
      k += dc.x * p.x - dc.y * p.y;
    }
    if (t == 0) k += dskip[L * 64 + d];
    Ks[t] = k;
  }
  __syncthreads();
  for (int s = t; s < 2048; s += 128) {
    int ln = s & 63, kt = (s >> 6) & 3, mt = s >> 8;
    int jo = mt * 16 + (ln & 15);
    int ji0 = kt * 32 + (ln >> 4) * 8;
    half8 v;
#pragma unroll
    for (int jj = 0; jj < 8; jj++) {
      int ji = ji0 + jj;
      v[jj] = (jo >= ji) ? (f16)Ks[jo - ji] : (f16)0.f;
    }
    TFl[(size_t)d * 2048 + s] = v;
  }
  for (int s = t; s < 512; s += 128) {
    int ln = s & 63, mt = s >> 6;
    int jo = mt * 16 + (ln & 15);
    int q0 = (ln >> 4) * 8;
    half8 v;
#pragma unroll
    for (int jj = 0; jj < 8; jj++) {
      int q = q0 + jj, n = q >> 1;
      f32x2 dc = dcS[n];
      f32x2 p = pw[jo + 1][n];
      float wr = dc.x * p.x - dc.y * p.y;
      float wi = dc.x * p.y + dc.y * p.x;
      v[jj] = (q & 1) ? (f16)(-wi) : (f16)wr;
    }
    VFl[(size_t)d * 512 + s] = v;
  }
  for (int s = t; s < 512; s += 128) {
    int ln = s & 63, kt = (s >> 6) & 3, nt = s >> 8;
    int p_ = nt * 16 + (ln & 15);
    int n = p_ >> 1;
    int j0 = kt * 32 + (ln >> 4) * 8;
    half8 v;
#pragma unroll
    for (int jj = 0; jj < 8; jj++) {
      f32x2 p = pw[127 - (j0 + jj)][n];
      v[jj] = (p_ & 1) ? (f16)p.y : (f16)p.x;
    }
    WFl[(size_t)d * 512 + s] = v;
  }
}

// -------- k_init3: x = relu(w_init*in + b_init) -> X f16; z = s4LN0(x) -> Z16 --------
__global__ __launch_bounds__(512) void k_init3(
    const float* __restrict__ inp, const float* __restrict__ w_init,
    const float* __restrict__ b_init, const float* __restrict__ lnw,
    const float* __restrict__ lnb, f16* __restrict__ X, f16* __restrict__ Z16) {
  __shared__ __align__(16) f16 ztile[64 * 132];
  int tid = threadIdx.x;
  int widx = tid >> 6, lane = tid & 63;
  int pl = lane & 15, qh = lane >> 4;
  for (int k = 0; k < 4; ++k) {
    int pt = blockIdx.x * 8 + widx + k * 4096;
    int pos = pt * 16 + pl;
    float v = inp[pos];
    float s = 0.f, s2 = 0.f;
    f32x4 o[4];
#pragma unroll
    for (int q = 0; q < 4; q++) {
      int d0 = q * 16 + qh * 4;
      f32x4 w4 = *(const f32x4*)(w_init + d0);
      f32x4 b4 = *(const f32x4*)(b_init + d0);
#pragma unroll
      for (int j = 0; j < 4; j++) {
        float t = fmaf(w4[j], v, b4[j]);
        t = t > 0.f ? t : 0.f;
        o[q][j] = t; s += t; s2 += t * t;
      }
      half4 xo = half4{(f16)o[q][0], (f16)o[q][1], (f16)o[q][2], (f16)o[q][3]};
      *(half4*)(X + (size_t)pos * 64 + d0) = xo;
    }
    s += __shfl_xor(s, 16); s += __shfl_xor(s, 32);
    s2 += __shfl_xor(s2, 16); s2 += __shfl_xor(s2, 32);
    float m = s * (1.0f / 64.0f);
    float rstd = rsqrtf(s2 * (1.0f / 64.0f) - m * m + 1e-5f);
    int prow = widx * 16 + pl;
#pragma unroll
    for (int q = 0; q < 4; q++) {
      int d0 = q * 16 + qh * 4;
      f32x4 lw = *(const f32x4*)(lnw + d0);
      f32x4 lb = *(const f32x4*)(lnb + d0);
#pragma unroll
      for (int r = 0; r < 4; r++)
        ztile[(d0 + r) * 132 + prow] = (f16)fmaf((o[q][r] - m) * rstd, lw[r], lb[r]);
    }
    __syncthreads();
    {
      int d = tid >> 3, c0 = (tid & 7) * 16;
      half8 z0 = *(const half8*)(ztile + d * 132 + c0);
      half8 z1 = *(const half8*)(ztile + d * 132 + c0 + 8);
      size_t zoff = (size_t)d * 262144 + (size_t)(blockIdx.x * 8 + k * 4096) * 16;
      *(half8*)(Z16 + zoff + c0) = z0;
      *(half8*)(Z16 + zoff + c0 + 8) = z1;
    }
    __syncthreads();
  }
}

// -------- k_p1g: chunk end-states S16[d][bc][p32] = Z(m=bc,k=j) @ Wend(k=j,n=p) --------
__global__ __launch_bounds__(256) void k_p1g(
    const f16* __restrict__ Z16, const half8* __restrict__ WF, f16* __restrict__ S16) {
  int tid = threadIdx.x;
  int lane = tid & 63;
  int task = blockIdx.x * 4 + (tid >> 6);
  int d = task >> 7, bct = task & 127;
  int bc0 = bct * 16;
  int pl = lane & 15, qh = lane >> 4;
  half8 az[4];
  const f16* zp = Z16 + ((size_t)d * 2048 + bc0 + pl) * 128 + qh * 8;
#pragma unroll
  for (int kt = 0; kt < 4; kt++) az[kt] = *(const half8*)(zp + kt * 32);
#pragma unroll
  for (int nt = 0; nt < 2; nt++) {
    f32x4 acc = f32x4{0.f, 0.f, 0.f, 0.f};
#pragma unroll
    for (int kt = 0; kt < 4; kt++)
      acc = __builtin_amdgcn_mfma_f32_16x16x32_f16(az[kt], WF[(size_t)d * 512 + (nt * 4 + kt) * 64 + lane], acc, 0, 0, 0);
#pragma unroll
    for (int r = 0; r < 4; r++)
      S16[((size_t)d * 2048 + bc0 + qh * 4 + r) * 32 + nt * 16 + pl] = (f16)acc[r];
  }
}

// -------- k_pass2: 3-phase block-local scan. grid 512 = (d,b); 256 thr = (g16, n16) --------
__global__ __launch_bounds__(256) void k_pass2(
    const f16* __restrict__ S16, const f32x2* __restrict__ LCLl,
    const f32x2* __restrict__ LC2Kl, f16* __restrict__ Sc) {
  __shared__ f32x2 gc[16][17];
  int blk = blockIdx.x;               // d*8 + b
  int d = blk >> 3, b = blk & 7;
  int t = threadIdx.x;                // g*16 + n
  int n = t & 15, g = t >> 4;
  f32x2 lam = LCLl[d * 16 + n];
  size_t base = ((size_t)d * 2048 + b * 256 + g * 16) * 32 + 2 * n;
  const f16* sp = S16 + base;
  float cr = 0.f, ci = 0.f;
#pragma unroll 4
  for (int j = 0; j < 16; j++) {
    half2t v = *(const half2t*)(sp + (size_t)j * 32);
    float nr = fmaf(lam.x, cr, fmaf(-lam.y, ci, (float)v[0]));
    float ni = fmaf(lam.x, ci, fmaf(lam.y, cr, (float)v[1]));
    cr = nr; ci = ni;
  }
  gc[g][n] = f32x2{cr, ci};
  __syncthreads();
  f32x2 l2 = LC2Kl[d * 16 + n];
  float er = 0.f, ei = 0.f;
  for (int gg = 0; gg < g; gg++) {
    f32x2 c = gc[gg][n];
    float nr = fmaf(l2.x, er, fmaf(-l2.y, ei, c.x));
    float ni = fmaf(l2.x, ei, fmaf(l2.y, er, c.y));
    er = nr; ei = ni;
  }
  f16* cp = Sc + base;
  float cr2 = er, ci2 = ei;
#pragma unroll 4
  for (int j = 0; j < 16; j++) {
    *(half2t*)(cp + (size_t)j * 32) = half2t{(f16)cr2, (f16)ci2};
    half2t v = *(const half2t*)(sp + (size_t)j * 32);
    float nr = fmaf(lam.x, cr2, fmaf(-lam.y, ci2, (float)v[0]));
    float ni = fmaf(lam.x, ci2, fmaf(lam.y, cr2, (float)v[1]));
    cr2 = nr; ci2 = ni;
  }
}

// -------- k_p3g2: y = T@z + V@carry, gelu -> Y16[pos][d] (d-packed half4) --------
__global__ __launch_bounds__(256) void k_p3g2(
    const f16* __restrict__ Z16, const f16* __restrict__ Sc,
    const half8* __restrict__ TF, const half8* __restrict__ VF,
    f16* __restrict__ Y16) {
  int tid = threadIdx.x;
  int lane = tid & 63, widx = tid >> 6;
  int bct = blockIdx.x & 127, dg = blockIdx.x >> 7;  // grid 512: 4 dg x 128 bct
  int bc0 = bct * 16;
  int dbase = dg * 16 + widx * 4;
  int pl = lane & 15, qh = lane >> 4;
  half8 zb[4][4];
  half8 sb[4];
#pragma unroll
  for (int di = 0; di < 4; di++) {
    int d = dbase + di;
    const f16* zp = Z16 + ((size_t)d * 2048 + bc0 + pl) * 128 + qh * 8;
#pragma unroll
    for (int kt = 0; kt < 4; kt++) zb[di][kt] = *(const half8*)(zp + kt * 32);
    sb[di] = *(const half8*)(Sc + ((size_t)d * 2048 + bc0 + pl) * 32 + qh * 8);
  }
#pragma unroll
  for (int mt = 0; mt < 8; mt++) {
    const int KTM = mt / 2 + 1;  // causal: tiles with ji0 <= jo_max
    f32x4 acc[4];
#pragma unroll
    for (int di = 0; di < 4; di++) {
      int d = dbase + di;
      acc[di] = f32x4{0.f, 0.f, 0.f, 0.f};
      const half8* tfp = TF + ((size_t)d * 8 + mt) * 256 + lane;
#pragma unroll
      for (int kt = 0; kt < KTM; kt++)
        acc[di] = __builtin_amdgcn_mfma_f32_16x16x32_f16(tfp[kt * 64], zb[di][kt], acc[di], 0, 0, 0);
      acc[di] = __builtin_amdgcn_mfma_f32_16x16x32_f16(VF[((size_t)d * 8 + mt) * 64 + lane], sb[di], acc[di], 0, 0, 0);
    }
#pragma unroll
    for (int r = 0; r < 4; r++) {
      int pos = (bc0 + pl) * 128 + mt * 16 + qh * 4 + r;
      half4 pk = half4{(f16)gelu_t(acc[0][r]), (f16)gelu_t(acc[1][r]),
                       (f16)gelu_t(acc[2][r]), (f16)gelu_t(acc[3][r])};
      *(half4*)(Y16 + (size_t)pos * 64 + dbase) = pk;
    }
  }
}

// ======== Fused GLU+FF(+next-layer z | +head); X residual stored f16, f32 in-register ========
template <int WZ>
__global__ __launch_bounds__(512) void k_gluff3(
    const f16* __restrict__ Y16, const float* __restrict__ Wg, const float* __restrict__ bg,
    const float* __restrict__ W1, const float* __restrict__ b1,
    const float* __restrict__ W2, const float* __restrict__ b2,
    const float* __restrict__ lnw, const float* __restrict__ lnb,
    const float* __restrict__ nlnw, const float* __restrict__ nlnb,
    f16* __restrict__ X, f16* __restrict__ Z16,
    const float* __restrict__ Wf, const float* __restrict__ bfb,
    const float* __restrict__ wz, const float* __restrict__ bz,
    float* __restrict__ outp) {
  __shared__ __align__(16) char smem[68352];
  int tid = threadIdx.x;
#pragma unroll
  for (int it = 0; it < 2; it++) {           // sWg: NATURAL k
    int s = it * 512 + tid;
    int l = s & 63, ks = (s >> 6) & 1, et = s >> 7;
    const float* wp = Wg + (et * 16 + (l & 15)) * 64 + ks * 32 + (l >> 4) * 8;
    f32x4 w0 = *(const f32x4*)wp, w1 = *(const f32x4*)(wp + 4);
    *(half8*)(smem + s * 16) = half8{(f16)w0[0], (f16)w0[1], (f16)w0[2], (f16)w0[3],
                                     (f16)w1[0], (f16)w1[1], (f16)w1[2], (f16)w1[3]};
  }
#pragma unroll
  for (int it = 0; it < 2; it++) {           // sW1: PERMUTED k
    int s = it * 512 + tid;
    int l = s & 63, ks = (s >> 6) & 1, et = s >> 7;
    int pls = l & 15, qhs = l >> 4;
    const float* wp = W1 + (et * 16 + pls) * 64 + ks * 32 + qhs * 4;
    f32x4 w0 = *(const f32x4*)wp;
    f32x4 w1 = *(const f32x4*)(wp + 16);
    *(half8*)(smem + 16384 + s * 16) = half8{(f16)w0[0], (f16)w0[1], (f16)w0[2], (f16)w0[3],
                                             (f16)w1[0], (f16)w1[1], (f16)w1[2], (f16)w1[3]};
  }
#pragma unroll
  for (int it = 0; it < 2; it++) {           // sW2: PERMUTED k
    int s = it * 512 + tid;
    int l = s & 63, ks = (s >> 6) & 3, dt = s >> 8;
    int pls = l & 15, qhs = l >> 4;
    const float* wp = W2 + (dt * 16 + pls) * 128 + ks * 32 + qhs * 4;
    f32x4 w0 = *(const f32x4*)wp;
    f32x4 w1 = *(const f32x4*)(wp + 16);
    *(half8*)(smem + 32768 + s * 16) = half8{(f16)w0[0], (f16)w0[1], (f16)w0[2], (f16)w0[3],
                                             (f16)w1[0], (f16)w1[1], (f16)w1[2], (f16)w1[3]};
  }
  for (int idx = tid; idx < 576; idx += 512) {
    float v;
    if (idx < 128) v = bg[idx];
    else if (idx < 256) v = b1[idx - 128];
    else if (idx < 320) v = b2[idx - 256];
    else if (idx < 384) v = lnw[idx - 320];
    else if (idx < 448) v = lnb[idx - 384];
    else if (idx < 512) v = nlnw[idx - 448];
    else v = nlnb[idx - 512];
    ((float*)(smem + 49152))[idx] = v;
  }
  if constexpr (!WZ) {
    if (tid < 512) {                         // sWf: PERMUTED k (head GEMM)
      int s = tid;
      int l = s & 63, ks = (s >> 6) & 1, et = s >> 7;  // et < 4
      int pls = l & 15, qhs = l >> 4;
      const float* wp = Wf + (et * 16 + pls) * 64 + ks * 32 + qhs * 4;
      f32x4 w0 = *(const f32x4*)wp;
      f32x4 w1 = *(const f32x4*)(wp + 16);
      *(half8*)(smem + 51456 + s * 16) = half8{(f16)w0[0], (f16)w0[1], (f16)w0[2], (f16)w0[3],
                                               (f16)w1[0], (f16)w1[1], (f16)w1[2], (f16)w1[3]};
    }
    if (tid < 129) {
      float v = tid < 64 ? bfb[tid] : (tid < 128 ? wz[tid - 64] : bz[0]);
      ((float*)(smem + 59648))[tid] = v;
    }
  }
  __syncthreads();
  int lane = tid & 63, pl = lane & 15, qh = lane >> 4;
  int widx = tid >> 6;
  f16* ztile = (f16*)(smem + 51456);

  for (int k = 0; k < 4; ++k) {
    int pt = blockIdx.x * 8 + widx + k * 4096;
    int pos = pt * 16 + pl;
    half8 yb0 = *(const half8*)(Y16 + (size_t)pos * 64 + qh * 8);
    half8 yb1 = *(const half8*)(Y16 + (size_t)pos * 64 + 32 + qh * 8);
    f32x4 xv[4];
#pragma unroll
    for (int q = 0; q < 4; q++) {
      half4 xh = *(const half4*)(X + (size_t)pos * 64 + q * 16 + qh * 4);
#pragma unroll
      for (int r = 0; r < 4; r++) xv[q][r] = (float)xh[r];
    }

    unsigned sb = 0;
    asm volatile("" : "+v"(sb));                // opaque: defeats LICM (anti-spill, R4-proven)
    const char* sm = smem + sb;
    const half8* sWg = (const half8*)sm;
    const half8* sW1 = (const half8*)(sm + 16384);
    const half8* sW2 = (const half8*)(sm + 32768);
    const float* sf = (const float*)(sm + 49152);
    // ---- GLU ----
    f32x4 accg[8];
#pragma unroll
    for (int et = 0; et < 8; et++) accg[et] = *(const f32x4*)(sf + et * 16 + qh * 4);
#pragma unroll
    for (int et = 0; et < 8; et++)
      accg[et] = __builtin_amdgcn_mfma_f32_16x16x32_f16(sWg[(et * 2) * 64 + lane], yb0, accg[et], 0, 0, 0);
#pragma unroll
    for (int et = 0; et < 8; et++)
      accg[et] = __builtin_amdgcn_mfma_f32_16x16x32_f16(sWg[(et * 2 + 1) * 64 + lane], yb1, accg[et], 0, 0, 0);
    float s = 0.f, s2 = 0.f;
#pragma unroll
    for (int q = 0; q < 4; q++)
#pragma unroll
      for (int r = 0; r < 4; r++) {
        xv[q][r] += accg[q][r] * sigm(accg[q + 4][r]);
        s += xv[q][r]; s2 += xv[q][r] * xv[q][r];
      }
    s += __shfl_xor(s, 16); s += __shfl_xor(s, 32);
    s2 += __shfl_xor(s2, 16); s2 += __shfl_xor(s2, 32);
    float m = s * (1.0f / 64.0f);
    float rstd = rsqrtf(s2 * (1.0f / 64.0f) - m * m + 1e-5f);
    // ---- FF GEMM1 (K=32 permuted frags) ----
    half4 zb4[4];
#pragma unroll
    for (int ks = 0; ks < 4; ks++) {
      f32x4 lw = *(const f32x4*)(sf + 320 + ks * 16 + qh * 4);
      f32x4 lb = *(const f32x4*)(sf + 384 + ks * 16 + qh * 4);
      half4 z;
#pragma unroll
      for (int r = 0; r < 4; r++) z[r] = (f16)fmaf((xv[ks][r] - m) * rstd, lw[r], lb[r]);
      zb4[ks] = z;
    }
    f32x4 acc1[8];
#pragma unroll
    for (int et = 0; et < 8; et++) acc1[et] = *(const f32x4*)(sf + 128 + et * 16 + qh * 4);
#pragma unroll
    for (int ks = 0; ks < 2; ks++) {
      half4 a = zb4[ks * 2], b = zb4[ks * 2 + 1];
      half8 zb8 = half8{a[0], a[1], a[2], a[3], b[0], b[1], b[2], b[3]};
#pragma unroll
      for (int et = 0; et < 8; et++)
        acc1[et] = __builtin_amdgcn_mfma_f32_16x16x32_f16(sW1[(et * 2 + ks) * 64 + lane], zb8, acc1[et], 0, 0, 0);
    }
    half4 h4[8];
#pragma unroll
    for (int et = 0; et < 8; et++)
      h4[et] = half4{(f16)gelu_t(acc1[et][0]), (f16)gelu_t(acc1[et][1]),
                     (f16)gelu_t(acc1[et][2]), (f16)gelu_t(acc1[et][3])};
    // ---- FF GEMM2 (K=128 as 4x32 permuted frags) ----
    f32x4 acc2[4];
#pragma unroll
    for (int dt = 0; dt < 4; dt++) acc2[dt] = *(const f32x4*)(sf + 256 + dt * 16 + qh * 4);
#pragma unroll
    for (int ks = 0; ks < 4; ks++) {
      half4 a = h4[ks * 2], b = h4[ks * 2 + 1];
      half8 hb8 = half8{a[0], a[1], a[2], a[3], b[0], b[1], b[2], b[3]};
#pragma unroll
      for (int dt = 0; dt < 4; dt++)
        acc2[dt] = __builtin_amdgcn_mfma_f32_16x16x32_f16(sW2[(dt * 4 + ks) * 64 + lane], hb8, acc2[dt], 0, 0, 0);
    }
    s = 0.f; s2 = 0.f;
#pragma unroll
    for (int dt = 0; dt < 4; dt++) {
#pragma unroll
      for (int r = 0; r < 4; r++) {
        xv[dt][r] += acc2[dt][r];
        s += xv[dt][r]; s2 += xv[dt][r] * xv[dt][r];
      }
      if constexpr (WZ) {
        half4 xo = half4{(f16)xv[dt][0], (f16)xv[dt][1], (f16)xv[dt][2], (f16)xv[dt][3]};
        *(half4*)(X + (size_t)pos * 64 + dt * 16 + qh * 4) = xo;
      }
    }
    s += __shfl_xor(s, 16); s += __shfl_xor(s, 32);
    s2 += __shfl_xor(s2, 16); s2 += __shfl_xor(s2, 32);
    float m2 = s * (1.0f / 64.0f);
    float rstd2 = rsqrtf(s2 * (1.0f / 64.0f) - m2 * m2 + 1e-5f);

    if constexpr (WZ) {
      int prow = widx * 16 + pl;
#pragma unroll
      for (int q = 0; q < 4; q++) {
        int d0 = q * 16 + qh * 4;
        f32x4 lw = *(const f32x4*)(sf + 448 + d0);
        f32x4 lb = *(const f32x4*)(sf + 512 + d0);
#pragma unroll
        for (int r = 0; r < 4; r++)
          ztile[(d0 + r) * 132 + prow] = (f16)fmaf((xv[q][r] - m2) * rstd2, lw[r], lb[r]);
      }
      __syncthreads();
      {
        int d = tid >> 3, c0 = (tid & 7) * 16;
        half8 z0 = *(const half8*)(ztile + d * 132 + c0);
        half8 z1 = *(const half8*)(ztile + d * 132 + c0 + 8);
        size_t zoff = (size_t)d * 262144 + (size_t)(blockIdx.x * 8 + k * 4096) * 16;
        *(half8*)(Z16 + zoff + c0) = z0;
        *(half8*)(Z16 + zoff + c0 + 8) = z1;
      }
      __syncthreads();
    } else {
      // ---- fused head: z = normLN(x); u = Wf z + bfb; o = wz . relu(u) + bz ----
      const half8* sWf = (const half8*)(sm + 51456);
      const float* hf = (const float*)(sm + 59648);
      half4 hz[4];
#pragma unroll
      for (int ks = 0; ks < 4; ks++) {
        f32x4 lw = *(const f32x4*)(sf + 448 + ks * 16 + qh * 4);
        f32x4 lb = *(const f32x4*)(sf + 512 + ks * 16 + qh * 4);
        half4 z;
#pragma unroll
        for (int r = 0; r < 4; r++) z[r] = (f16)fmaf((xv[ks][r] - m2) * rstd2, lw[r], lb[r]);
        hz[ks] = z;
      }
      f32x4 acch[4];
#pragma unroll
      for (int et = 0; et < 4; et++) acch[et] = *(const f32x4*)(hf + et * 16 + qh * 4);
#pragma unroll
      for (int ks = 0; ks < 2; ks++) {
        half4 a = hz[ks * 2], b = hz[ks * 2 + 1];
        half8 zb8 = half8{a[0], a[1], a[2], a[3], b[0], b[1], b[2], b[3]};
#pragma unroll
        for (int et = 0; et < 4; et++)
          acch[et] = __builtin_amdgcn_mfma_f32_16x16x32_f16(sWf[(et * 2 + ks) * 64 + lane], zb8, acch[et], 0, 0, 0);
      }
      float o = 0.f;
#pragma unroll
      for (int et = 0; et < 4; et++) {
        f32x4 wzv = *(const f32x4*)(hf + 64 + et * 16 + qh * 4);
#pragma unroll
        for (int r = 0; r < 4; r++) {
          float rv = acch[et][r];
          rv = rv > 0.f ? rv : 0.f;
          o = fmaf(wzv[r], rv, o);
        }
      }
      o += __shfl_xor(o, 16); o += __shfl_xor(o, 32);
      if (qh == 0) outp[pos] = o + hf[128];
    }
  }
}

extern "C" void kernel_launch(void* const* d_in, const int* in_sizes, int n_in,
                              void* d_out, int out_size, void* d_ws, size_t ws_size,
                              hipStream_t stream) {
  (void)in_sizes; (void)n_in; (void)out_size; (void)ws_size;
  const float* inputs   = (const float*)d_in[0];
  const float* w_init   = (const float*)d_in[1];
  const float* b_init   = (const float*)d_in[2];
  const float* s4_ln_w  = (const float*)d_in[3];
  const float* s4_ln_b  = (const float*)d_in[4];
  const float* log_dt   = (const float*)d_in[5];
  const float* log_A    = (const float*)d_in[6];
  const float* A_imag   = (const float*)d_in[7];
  const float* C_re     = (const float*)d_in[8];
  const float* C_im     = (const float*)d_in[9];
  const float* D_skip   = (const float*)d_in[10];
  const float* s4_out_w = (const float*)d_in[11];
  const float* s4_out_b = (const float*)d_in[12];
  const float* ff_ln_w  = (const float*)d_in[13];
  const float* ff_ln_b  = (const float*)d_in[14];
  const float* ff_w1    = (const float*)d_in[15];
  const float* ff_b1    = (const float*)d_in[16];
  const float* ff_w2    = (const float*)d_in[17];
  const float* ff_b2    = (const float*)d_in[18];
  const float* norm_w   = (const float*)d_in[19];
  const float* norm_b   = (const float*)d_in[20];
  const float* w_final1 = (const float*)d_in[21];
  const float* b_final1 = (const float*)d_in[22];
  const float* w_zero   = (const float*)d_in[23];
  const float* b_zero   = (const float*)d_in[24];

  char* w8 = (char*)d_ws;
  size_t off = 0;
  f16*   X     = (f16*)(w8 + off);   off += (size_t)33554432;   // [pos][64] f16
  f16*   Z16   = (f16*)(w8 + off);   off += (size_t)33554432;   // [d][pos] f16
  f16*   Y16   = (f16*)(w8 + off);   off += (size_t)33554432;   // [pos][d] f16
  f16*   S16   = (f16*)(w8 + off);   off += (size_t)8388608;    // [d][bc][32] f16
  f16*   Sc    = (f16*)(w8 + off);   off += (size_t)8388608;    // [d][bc][32] f16
  f32x2* LCL   = (f32x2*)(w8 + off); off += 32768;
  f32x2* LC2K  = (f32x2*)(w8 + off); off += 32768;
  half8* TF    = (half8*)(w8 + off); off += (size_t)8388608;    // 4 layers x 2MB
  half8* VF    = (half8*)(w8 + off); off += (size_t)2097152;
  half8* WF    = (half8*)(w8 + off); off += (size_t)2097152;

  k_wtall<<<256, 128, 0, stream>>>(log_dt, log_A, A_imag, C_re, C_im, D_skip,
                                   LCL, LC2K, TF, VF, WF);
  k_init3<<<512, 512, 0, stream>>>(inputs, w_init, b_init, s4_ln_w, s4_ln_b, X, Z16);
  for (int i = 0; i < NLq; i++) {
    k_p1g<<<2048, 256, 0, stream>>>(Z16, WF + (size_t)i * 32768, S16);
    k_pass2<<<512, 256, 0, stream>>>(S16, LCL + i * 1024, LC2K + i * 1024, Sc);
    k_p3g2<<<512, 256, 0, stream>>>(Z16, Sc, TF + (size_t)i * 131072, VF + (size_t)i * 32768, Y16);
    if (i < NLq - 1) {
      k_gluff3<1><<<512, 512, 0, stream>>>(Y16, s4_out_w + i * 8192, s4_out_b + i * 128,
                                           ff_w1 + i * 8192, ff_b1 + i * 128,
                                           ff_w2 + i * 8192, ff_b2 + i * 64,
                                           ff_ln_w + i * 64, ff_ln_b + i * 64,
                                           s4_ln_w + (i + 1) * 64, s4_ln_b + (i + 1) * 64,
                                           X, Z16, nullptr, nullptr, nullptr, nullptr, nullptr);
    } else {
      k_gluff3<0><<<512, 512, 0, stream>>>(Y16, s4_out_w + i * 8192, s4_out_b + i * 128,
                                           ff_w1 + i * 8192, ff_b1 + i * 128,
                                           ff_w2 + i * 8192, ff_b2 + i * 64,
                                           ff_ln_w + i * 64, ff_ln_b + i * 64,
                                           norm_w, norm_b,
                                           X, Z16, w_final1, b_final1, w_zero, b_zero,
                                           (float*)d_out);
    }
  }
}